// Round 5
// baseline (920.789 us; speedup 1.0000x reference)
//
#include <hip/hip_runtime.h>

#define NW 30000
#define ND 8192
#define DIM 300
#define DIM2 150
#define NNZA 600000
#define NNZX 524288
#define PD 320            // padded feature stride (bf16 elems)
#define PD_U 160          // padded stride in uint (2 bf16 each)
#define BN_SCALE 0.99999500003749971f

typedef unsigned int uint;
typedef unsigned short ushort;
typedef __attribute__((ext_vector_type(8))) short bf16x8;
typedef __attribute__((ext_vector_type(4))) float f32x4;
typedef __attribute__((ext_vector_type(4))) uint uint4v;

static inline int cdiv(int a, int b){ return (a + b - 1) / b; }

__device__ __forceinline__ float b2f_lo(uint u){ return __builtin_bit_cast(float, u << 16); }
__device__ __forceinline__ float b2f_hi(uint u){ return __builtin_bit_cast(float, u & 0xffff0000u); }
__device__ __forceinline__ ushort f2b(float f){
  uint u = __builtin_bit_cast(uint, f);
  u += 0x7fffu + ((u >> 16) & 1u);
  return (ushort)(u >> 16);
}
__device__ __forceinline__ uint packb(float x, float y){
  return (uint)f2b(x) | ((uint)f2b(y) << 16);
}

// ---------------- CSR build ----------------
__global__ void k_hist(const int* __restrict__ rows, int n, int* __restrict__ cnt){
  int i = blockIdx.x * blockDim.x + threadIdx.x;
  if (i < n) atomicAdd(&cnt[rows[i]], 1);
}

__global__ void k_copy_int(const int* __restrict__ a, int* __restrict__ b, int n){
  int i = blockIdx.x * blockDim.x + threadIdx.x;
  if (i < n) b[i] = a[i];
}

// hierarchical scan: (1) per-1024-block sums
__global__ __launch_bounds__(1024) void k_bsum(const int* __restrict__ cnt, int n, int* __restrict__ bs){
  __shared__ int sd[1024];
  int t = threadIdx.x;
  int i = blockIdx.x * 1024 + t;
  sd[t] = (i < n) ? cnt[i] : 0;
  __syncthreads();
  #pragma unroll
  for (int o = 512; o > 0; o >>= 1){
    if (t < o) sd[t] += sd[t + o];
    __syncthreads();
  }
  if (t == 0) bs[blockIdx.x] = sd[0];
}

// (2) single-wave exclusive scan of block sums (nb <= 64), writes total to rp[n]
__global__ __launch_bounds__(64) void k_scan_small(int* __restrict__ bs, int nb,
                                                   int* __restrict__ rp, int n){
  int t = threadIdx.x;
  int orig = (t < nb) ? bs[t] : 0;
  int v = orig;
  #pragma unroll
  for (int o = 1; o < 64; o <<= 1){
    int x = __shfl_up(v, o);
    if (t >= o) v += x;
  }
  if (t < nb) bs[t] = v - orig;
  if (t == nb - 1) rp[n] = v;
}

// (3) per-block scan + offset
__global__ __launch_bounds__(1024) void k_scan_apply(const int* __restrict__ cnt, int n,
        const int* __restrict__ bs, int* __restrict__ rp){
  __shared__ int sd[1024];
  int t = threadIdx.x;
  int i = blockIdx.x * 1024 + t;
  int v = (i < n) ? cnt[i] : 0;
  sd[t] = v;
  __syncthreads();
  for (int o = 1; o < 1024; o <<= 1){
    int x = (t >= o) ? sd[t - o] : 0;
    __syncthreads();
    sd[t] += x;
    __syncthreads();
  }
  if (i < n) rp[i] = bs[blockIdx.x] + sd[t] - v;
}

__global__ void k_scatter(const int* __restrict__ rows, const int* __restrict__ cols,
                          const float* __restrict__ vals, int n, int* __restrict__ cursor,
                          int* __restrict__ cs, float* __restrict__ vs){
  int i = blockIdx.x * blockDim.x + threadIdx.x;
  if (i < n){
    int r = rows[i];
    int p = atomicAdd(&cursor[r], 1);
    cs[p] = cols[i];
    vs[p] = vals[i];
  }
}

// ---------------- fp32 -> bf16 pad-convert, 8 cols/thread, uint4 stores ----------------
__global__ void k_f2b_pad8(const float* __restrict__ src, ushort* __restrict__ dst,
                           int srows, int scols, int drows, int dstride){
  int q = blockIdx.x * blockDim.x + threadIdx.x;   // one q = 8 output cols
  int perRow = dstride >> 3;
  int r = q / perRow;
  int c = (q - r * perRow) << 3;
  if (r >= drows) return;
  float x[8];
  #pragma unroll
  for (int j = 0; j < 8; ++j)
    x[j] = (r < srows && c + j < scols) ? src[(size_t)r * scols + c + j] : 0.f;
  uint4v o;
  o.x = packb(x[0], x[1]); o.y = packb(x[2], x[3]);
  o.z = packb(x[4], x[5]); o.w = packb(x[6], x[7]);
  *(uint4v*)(dst + (size_t)r * dstride + c) = o;
}

// ---------------- XCD-sliced SpMM over bf16 table ----------------
// blockIdx.x = rb*8 + slice; slice s -> XCD s (HW round-robin), slice table = 2.4 MB,
// L2-resident per XCD. Wave = 3 rows x 20 lanes (1 uint = 2 bf16 cols per lane), unroll-2.
__global__ __launch_bounds__(256) void k_spmm_sl(const int* __restrict__ rp, const int* __restrict__ cs,
        const float* __restrict__ vs, const uint* __restrict__ Hb, uint* __restrict__ Ob, int nrows){
  const int b  = blockIdx.x;
  const int sl = b & 7;
  const int rb = b >> 3;
  const int wv = threadIdx.x >> 6;
  const int lane = threadIdx.x & 63;
  const int rl = lane / 20;              // 0..2 (rl==3: lanes 60-63 idle)
  const int c  = lane - rl * 20;
  const int row = (rb * 4 + wv) * 3 + rl;
  const bool act = (rl < 3) && (row < nrows);
  int s = 0, e = 0;
  if (act){ s = rp[row]; e = rp[row + 1]; }
  int len = e - s;
  // max nnz among the wave's rows
  int mx = len;
  #pragma unroll
  for (int o = 32; o > 0; o >>= 1) mx = max(mx, __shfl_down(mx, o));
  mx = __shfl(mx, 0);
  const uint* base = Hb + sl * 20 + c;
  float aL0 = 0.f, aH0 = 0.f, aL1 = 0.f, aH1 = 0.f;
  for (int i = 0; i < mx; i += 2){
    int k0 = s + i, k1 = s + i + 1;
    bool p0 = act && (k0 < e);
    bool p1 = act && (k1 < e);
    int  c0 = p0 ? cs[k0] : 0;
    int  c1 = p1 ? cs[k1] : 0;
    float v0 = p0 ? vs[k0] : 0.f;
    float v1 = p1 ? vs[k1] : 0.f;
    uint u0 = p0 ? base[(size_t)c0 * PD_U] : 0u;
    uint u1 = p1 ? base[(size_t)c1 * PD_U] : 0u;
    aL0 = fmaf(v0, b2f_lo(u0), aL0); aH0 = fmaf(v0, b2f_hi(u0), aH0);
    aL1 = fmaf(v1, b2f_lo(u1), aL1); aH1 = fmaf(v1, b2f_hi(u1), aH1);
  }
  if (act) Ob[(size_t)row * PD_U + sl * 20 + c] = packb(aL0 + aL1, aH0 + aH1);
}

// ---------------- MFMA GEMM: C[M,Nvalid] = act(A[M,320]bf16 @ B[n][k]bf16^T) ----------------
// BM=128, BN=160, BK=64, 4 waves (2x2), wave tile 64x80 (4x5 16x16 frags).
__global__ __launch_bounds__(256) void k_mgemm(const ushort* __restrict__ A, const ushort* __restrict__ B,
        const float* __restrict__ bias, const float* __restrict__ bng, const float* __restrict__ bnb,
        ushort* __restrict__ C, int M, int Nvalid, int ldc, int relu){
  __shared__ ushort As[128][72];
  __shared__ ushort Bs[160][72];
  const int t = threadIdx.x;
  const int wid = t >> 6, lane = t & 63;
  const int bm = blockIdx.y << 7;
  const int bn = blockIdx.x * 160;
  const int wm = (wid >> 1) << 6;   // 0 / 64
  const int wn = (wid & 1) * 80;    // 0 / 80
  const int r16 = lane & 15;
  const int h8 = (lane >> 4) << 3;  // k-offset within 32
  f32x4 acc[4][5] = {};
  for (int k0 = 0; k0 < PD; k0 += 64){
    #pragma unroll
    for (int i = 0; i < 4; ++i){
      int q = t + (i << 8);
      int r = q >> 3, c = (q & 7) << 3;
      int gm = bm + r; if (gm >= M) gm = M - 1;
      *(bf16x8*)(&As[r][c]) = *(const bf16x8*)(A + (size_t)gm * PD + k0 + c);
    }
    #pragma unroll
    for (int i = 0; i < 5; ++i){
      int q = t + (i << 8);
      int r = q >> 3, c = (q & 7) << 3;
      *(bf16x8*)(&Bs[r][c]) = *(const bf16x8*)(B + (size_t)(bn + r) * PD + k0 + c);
    }
    __syncthreads();
    #pragma unroll
    for (int kk = 0; kk < 2; ++kk){
      bf16x8 af[4], bfr[5];
      #pragma unroll
      for (int m = 0; m < 4; ++m)
        af[m] = *(const bf16x8*)(&As[wm + m * 16 + r16][kk * 32 + h8]);
      #pragma unroll
      for (int n = 0; n < 5; ++n)
        bfr[n] = *(const bf16x8*)(&Bs[wn + n * 16 + r16][kk * 32 + h8]);
      #pragma unroll
      for (int m = 0; m < 4; ++m)
        #pragma unroll
        for (int n = 0; n < 5; ++n)
          acc[m][n] = __builtin_amdgcn_mfma_f32_16x16x32_bf16(af[m], bfr[n], acc[m][n], 0, 0, 0);
    }
    __syncthreads();
  }
  const int cr = (lane >> 4) << 2;
  #pragma unroll
  for (int m = 0; m < 4; ++m){
    #pragma unroll
    for (int n = 0; n < 5; ++n){
      int col = bn + wn + n * 16 + r16;
      #pragma unroll
      for (int j = 0; j < 4; ++j){
        int row = bm + wm + m * 16 + cr + j;
        if (row >= M) continue;
        float v = acc[m][n][j];
        if (col < Nvalid){
          if (bias) v += bias[col];
          if (bng)  v = v * (bng[col] * BN_SCALE) + bnb[col];
          if (relu) v = fmaxf(v, 0.f);
        } else v = 0.f;
        C[(size_t)row * ldc + col] = f2b(v);
      }
    }
  }
}

// ---------------- residual + LayerNorm; S = LN(0.3*emb + 0.7*H) + emb (bf16 out, padded) ----------------
__global__ __launch_bounds__(64) void k_res_ln(const float* __restrict__ emb, const uint* __restrict__ Hb,
        const float* __restrict__ g, const float* __restrict__ bb, uint* __restrict__ S){
  int row = blockIdx.x, lane = threadIdx.x;
  const float* e = emb + (size_t)row * DIM;
  const uint* h = Hb + (size_t)row * PD_U;
  float x[6], ev[6];
  float sum = 0.f, sq = 0.f;
  #pragma unroll
  for (int j = 0; j < 3; ++j){
    int i = lane + j * 64;
    float e0 = 0.f, e1 = 0.f, h0 = 0.f, h1 = 0.f;
    if (i < 150){
      uint u = h[i];
      h0 = b2f_lo(u); h1 = b2f_hi(u);
      e0 = e[2 * i]; e1 = e[2 * i + 1];
    }
    float v0 = 0.3f * e0 + 0.7f * h0;
    float v1 = 0.3f * e1 + 0.7f * h1;
    if (i >= 150){ v0 = 0.f; v1 = 0.f; }
    x[2*j] = v0; x[2*j+1] = v1; ev[2*j] = e0; ev[2*j+1] = e1;
    sum += v0 + v1; sq += v0 * v0 + v1 * v1;
  }
  #pragma unroll
  for (int o = 32; o > 0; o >>= 1){ sum += __shfl_down(sum, o); sq += __shfl_down(sq, o); }
  sum = __shfl(sum, 0); sq = __shfl(sq, 0);
  const float inv = 1.f / (float)DIM;
  float mu = sum * inv;
  float var = sq * inv - mu * mu;
  float rs = rsqrtf(var + 1e-5f);
  uint* o = S + (size_t)row * PD_U;
  #pragma unroll
  for (int j = 0; j < 3; ++j){
    int i = lane + j * 64;
    if (i >= PD_U) continue;
    uint w = 0;
    if (i < 150){
      float r0 = (x[2*j]   - mu) * rs * g[2*i]   + bb[2*i]   + ev[2*j];
      float r1 = (x[2*j+1] - mu) * rs * g[2*i+1] + bb[2*i+1] + ev[2*j+1];
      w = packb(r0, r1);
    }
    o[i] = w;
  }
}

// ---------------- classifier: [ND,150]bf16 @ [2,150]^T + b -> fp32 out ----------------
__global__ void k_clf(const uint* __restrict__ h2, const float* __restrict__ w,
                      const float* __restrict__ bias, float* __restrict__ out){
  int m = blockIdx.x * blockDim.x + threadIdx.x;
  if (m >= ND) return;
  const uint* hr = h2 + (size_t)m * 80;
  float s0 = bias[0], s1 = bias[1];
  #pragma unroll 5
  for (int i = 0; i < 75; ++i){
    uint u = hr[i];
    float h0 = b2f_lo(u), h1 = b2f_hi(u);
    int k = 2 * i;
    s0 = fmaf(h0, w[k], fmaf(h1, w[k + 1], s0));
    s1 = fmaf(h0, w[DIM2 + k], fmaf(h1, w[DIM2 + k + 1], s1));
  }
  out[m * 2] = s0;
  out[m * 2 + 1] = s1;
}

extern "C" void kernel_launch(void* const* d_in, const int* in_sizes, int n_in,
                              void* d_out, int out_size, void* d_ws, size_t ws_size,
                              hipStream_t stream){
  const int*   a_rows = (const int*)  d_in[0];
  const int*   a_cols = (const int*)  d_in[1];
  const float* a_vals = (const float*)d_in[2];
  const int*   x_rows = (const int*)  d_in[3];
  const int*   x_cols = (const int*)  d_in[4];
  const float* x_vals = (const float*)d_in[5];
  const float* emb    = (const float*)d_in[6];
  const float* w1     = (const float*)d_in[7];
  const float* w2     = (const float*)d_in[8];
  const float* w3     = (const float*)d_in[9];
  const float* ln_g   = (const float*)d_in[10];
  const float* ln_b   = (const float*)d_in[11];
  const float* m_w1   = (const float*)d_in[12];
  const float* m_b1   = (const float*)d_in[13];
  const float* bn1_g  = (const float*)d_in[14];
  const float* bn1_b  = (const float*)d_in[15];
  const float* m_w2   = (const float*)d_in[16];
  const float* m_b2   = (const float*)d_in[17];
  const float* bn2_g  = (const float*)d_in[18];
  const float* bn2_b  = (const float*)d_in[19];
  const float* clf_w  = (const float*)d_in[20];
  const float* clf_b  = (const float*)d_in[21];
  float* out = (float*)d_out;

  char* ws = (char*)d_ws;
  size_t off = 0;
  auto take = [&](size_t nbytes)->void*{
    void* p = ws + off;
    off += (nbytes + 255) & ~(size_t)255;
    return p;
  };
  int*    a_rp   = (int*)   take((NW + 1) * 4);
  int*    a_cs   = (int*)   take((size_t)NNZA * 4);
  float*  a_vs   = (float*) take((size_t)NNZA * 4);
  int*    x_rp   = (int*)   take((ND + 1) * 4);
  int*    x_cs   = (int*)   take((size_t)NNZX * 4);
  float*  x_vs   = (float*) take((size_t)NNZX * 4);
  int*    cursor = (int*)   take((size_t)NW * 4);
  int*    bsums  = (int*)   take(64 * 4);
  ushort* embb   = (ushort*)take((size_t)NW * PD * 2);
  ushort* Tb     = (ushort*)take((size_t)NW * PD * 2);
  ushort* Hb     = (ushort*)take((size_t)NW * PD * 2);
  ushort* w1b    = (ushort*)take((size_t)PD * PD * 2);
  ushort* w2b    = (ushort*)take((size_t)PD * PD * 2);
  ushort* w3b    = (ushort*)take((size_t)PD * PD * 2);
  ushort* mw1b   = (ushort*)take((size_t)PD * PD * 2);
  ushort* mw2b   = (ushort*)take((size_t)PD * PD * 2);
  // doc-stage buffers alias Hb (H3 is dead once res_ln has produced S in Tb)
  ushort* docHb = Hb;
  ushort* h1b   = Hb + (size_t)ND * PD;
  ushort* h2b   = Hb + (size_t)2 * ND * PD;  // stride 160

  // ---- CSR build for A ----
  int nbA = cdiv(NW, 1024);
  hipMemsetAsync(cursor, 0, NW * 4, stream);
  k_hist<<<cdiv(NNZA, 256), 256, 0, stream>>>(a_rows, NNZA, cursor);
  k_bsum<<<nbA, 1024, 0, stream>>>(cursor, NW, bsums);
  k_scan_small<<<1, 64, 0, stream>>>(bsums, nbA, a_rp, NW);
  k_scan_apply<<<nbA, 1024, 0, stream>>>(cursor, NW, bsums, a_rp);
  k_copy_int<<<cdiv(NW, 256), 256, 0, stream>>>(a_rp, cursor, NW);
  k_scatter<<<cdiv(NNZA, 256), 256, 0, stream>>>(a_rows, a_cols, a_vals, NNZA, cursor, a_cs, a_vs);
  // ---- CSR build for X ----
  int nbX = cdiv(ND, 1024);
  hipMemsetAsync(cursor, 0, ND * 4, stream);
  k_hist<<<cdiv(NNZX, 256), 256, 0, stream>>>(x_rows, NNZX, cursor);
  k_bsum<<<nbX, 1024, 0, stream>>>(cursor, ND, bsums);
  k_scan_small<<<1, 64, 0, stream>>>(bsums, nbX, x_rp, ND);
  k_scan_apply<<<nbX, 1024, 0, stream>>>(cursor, ND, bsums, x_rp);
  k_copy_int<<<cdiv(ND, 256), 256, 0, stream>>>(x_rp, cursor, ND);
  k_scatter<<<cdiv(NNZX, 256), 256, 0, stream>>>(x_rows, x_cols, x_vals, NNZX, cursor, x_cs, x_vs);

  // ---- fp32 -> bf16 padded conversions (8 cols/thread) ----
  k_f2b_pad8<<<cdiv(NW * 40, 256), 256, 0, stream>>>(emb, embb, NW, DIM, NW, PD);
  k_f2b_pad8<<<cdiv(PD * 40, 256), 256, 0, stream>>>(w1, w1b, DIM, DIM, PD, PD);
  k_f2b_pad8<<<cdiv(PD * 40, 256), 256, 0, stream>>>(w2, w2b, DIM, DIM, PD, PD);
  k_f2b_pad8<<<cdiv(PD * 40, 256), 256, 0, stream>>>(w3, w3b, DIM, DIM, PD, PD);
  k_f2b_pad8<<<cdiv(PD * 40, 256), 256, 0, stream>>>(m_w1, mw1b, DIM, DIM, PD, PD);
  k_f2b_pad8<<<cdiv(PD * 40, 256), 256, 0, stream>>>(m_w2, mw2b, DIM2, DIM, PD, PD);

  // ---- word GCN (sliced SpMM: grid = rowgroups*8 slices) ----
  int gsA = cdiv(NW, 12) * 8;
  int gsX = cdiv(ND, 12) * 8;
  dim3 gg(2, cdiv(NW, 128));
  k_spmm_sl<<<gsA, 256, 0, stream>>>(a_rp, a_cs, a_vs, (const uint*)embb, (uint*)Tb, NW);
  k_mgemm<<<gg, 256, 0, stream>>>(Tb, w1b, nullptr, nullptr, nullptr, Hb, NW, DIM, PD, 1);
  k_spmm_sl<<<gsA, 256, 0, stream>>>(a_rp, a_cs, a_vs, (const uint*)Hb, (uint*)Tb, NW);
  k_mgemm<<<gg, 256, 0, stream>>>(Tb, w2b, nullptr, nullptr, nullptr, Hb, NW, DIM, PD, 1);
  k_spmm_sl<<<gsA, 256, 0, stream>>>(a_rp, a_cs, a_vs, (const uint*)Hb, (uint*)Tb, NW);
  k_mgemm<<<gg, 256, 0, stream>>>(Tb, w3b, nullptr, nullptr, nullptr, Hb, NW, DIM, PD, 1);
  // ---- residual + LN (S = LN + emb fused into Tb) ----
  k_res_ln<<<NW, 64, 0, stream>>>(emb, (const uint*)Hb, ln_g, ln_b, (uint*)Tb);
  // ---- doc aggregation (single sliced SpMM over summed matrix) ----
  k_spmm_sl<<<gsX, 256, 0, stream>>>(x_rp, x_cs, x_vs, (const uint*)Tb, (uint*)docHb, ND);
  // ---- MLP head ----
  dim3 g1(2, cdiv(ND, 128));
  k_mgemm<<<g1, 256, 0, stream>>>(docHb, mw1b, m_b1, bn1_g, bn1_b, h1b, ND, DIM, PD, 1);
  dim3 g2(1, cdiv(ND, 128));
  k_mgemm<<<g2, 256, 0, stream>>>(h1b, mw2b, m_b2, bn2_g, bn2_b, h2b, ND, DIM2, 160, 1);
  k_clf<<<cdiv(ND, 256), 256, 0, stream>>>((const uint*)h2b, clf_w, clf_b, out);
}

// Round 6
// 685.918 us; speedup vs baseline: 1.3424x; 1.3424x over previous
//
#include <hip/hip_runtime.h>

#define NW 30000
#define ND 8192
#define DIM 300
#define DIM2 150
#define NNZA 600000
#define NNZX 524288
#define PD 320            // padded feature stride (bf16 elems)
#define PD_U 160          // padded stride in uint (2 bf16 each)
#define BN_SCALE 0.99999500003749971f

typedef unsigned int uint;
typedef unsigned short ushort;
typedef __attribute__((ext_vector_type(8))) short bf16x8;
typedef __attribute__((ext_vector_type(4))) float f32x4;
typedef __attribute__((ext_vector_type(4))) uint uint4v;

static inline int cdiv(int a, int b){ return (a + b - 1) / b; }

__device__ __forceinline__ float b2f_lo(uint u){ return __builtin_bit_cast(float, u << 16); }
__device__ __forceinline__ float b2f_hi(uint u){ return __builtin_bit_cast(float, u & 0xffff0000u); }
__device__ __forceinline__ ushort f2b(float f){
  uint u = __builtin_bit_cast(uint, f);
  u += 0x7fffu + ((u >> 16) & 1u);
  return (ushort)(u >> 16);
}
__device__ __forceinline__ uint packb(float x, float y){
  return (uint)f2b(x) | ((uint)f2b(y) << 16);
}

// ---------------- CSR build ----------------
__global__ void k_hist(const int* __restrict__ rows, int n, int* __restrict__ cnt){
  int i = blockIdx.x * blockDim.x + threadIdx.x;
  if (i < n) atomicAdd(&cnt[rows[i]], 1);
}

__global__ void k_copy_int(const int* __restrict__ a, int* __restrict__ b, int n){
  int i = blockIdx.x * blockDim.x + threadIdx.x;
  if (i < n) b[i] = a[i];
}

// hierarchical scan: (1) per-1024-block sums
__global__ __launch_bounds__(1024) void k_bsum(const int* __restrict__ cnt, int n, int* __restrict__ bs){
  __shared__ int sd[1024];
  int t = threadIdx.x;
  int i = blockIdx.x * 1024 + t;
  sd[t] = (i < n) ? cnt[i] : 0;
  __syncthreads();
  #pragma unroll
  for (int o = 512; o > 0; o >>= 1){
    if (t < o) sd[t] += sd[t + o];
    __syncthreads();
  }
  if (t == 0) bs[blockIdx.x] = sd[0];
}

// (2) single-wave exclusive scan of block sums (nb <= 64), writes total to rp[n]
__global__ __launch_bounds__(64) void k_scan_small(int* __restrict__ bs, int nb,
                                                   int* __restrict__ rp, int n){
  int t = threadIdx.x;
  int orig = (t < nb) ? bs[t] : 0;
  int v = orig;
  #pragma unroll
  for (int o = 1; o < 64; o <<= 1){
    int x = __shfl_up(v, o);
    if (t >= o) v += x;
  }
  if (t < nb) bs[t] = v - orig;
  if (t == nb - 1) rp[n] = v;
}

// (3) per-block scan + offset
__global__ __launch_bounds__(1024) void k_scan_apply(const int* __restrict__ cnt, int n,
        const int* __restrict__ bs, int* __restrict__ rp){
  __shared__ int sd[1024];
  int t = threadIdx.x;
  int i = blockIdx.x * 1024 + t;
  int v = (i < n) ? cnt[i] : 0;
  sd[t] = v;
  __syncthreads();
  for (int o = 1; o < 1024; o <<= 1){
    int x = (t >= o) ? sd[t - o] : 0;
    __syncthreads();
    sd[t] += x;
    __syncthreads();
  }
  if (i < n) rp[i] = bs[blockIdx.x] + sd[t] - v;
}

__global__ void k_scatter(const int* __restrict__ rows, const int* __restrict__ cols,
                          const float* __restrict__ vals, int n, int* __restrict__ cursor,
                          int* __restrict__ cs, float* __restrict__ vs){
  int i = blockIdx.x * blockDim.x + threadIdx.x;
  if (i < n){
    int r = rows[i];
    int p = atomicAdd(&cursor[r], 1);
    cs[p] = cols[i];
    vs[p] = vals[i];
  }
}

// ---------------- fp32 -> bf16 pad-convert, 8 cols/thread, uint4 stores ----------------
// slcRows>0: write slice-major T[sl][slcRows][40] (sl = col/40)
__global__ void k_f2b_pad8(const float* __restrict__ src, ushort* __restrict__ dst,
                           int srows, int scols, int drows, int dstride, int slcRows){
  int q = blockIdx.x * blockDim.x + threadIdx.x;   // one q = 8 output cols
  int perRow = dstride >> 3;
  int r = q / perRow;
  int c = (q - r * perRow) << 3;
  if (r >= drows) return;
  float x[8];
  #pragma unroll
  for (int j = 0; j < 8; ++j)
    x[j] = (r < srows && c + j < scols) ? src[(size_t)r * scols + c + j] : 0.f;
  uint4v o;
  o.x = packb(x[0], x[1]); o.y = packb(x[2], x[3]);
  o.z = packb(x[4], x[5]); o.w = packb(x[6], x[7]);
  if (slcRows > 0){
    int sl = c / 40, cc = c % 40;
    *(uint4v*)(dst + ((size_t)sl * slcRows + r) * 40 + cc) = o;
  } else {
    *(uint4v*)(dst + (size_t)r * dstride + c) = o;
  }
}

// ---------------- XCD-sliced SpMM, slice-major table ----------------
// blockIdx.x = rb*8 + sl  ->  slice sl pinned to XCD sl (HW round-robin).
// Table T: uint view, slice-major [8][tabRows][20]. Slice region = tabRows*80 B (2.4 MB @ NW).
// One row per wave; 3 nnz in parallel via 3 groups x 20 lanes; unroll-2.
// Output O row-major [nrows][PD_U].
__global__ __launch_bounds__(256) void k_spmm_s2(const int* __restrict__ rp, const int* __restrict__ cs,
        const float* __restrict__ vs, const uint* __restrict__ T, uint* __restrict__ O,
        int nrows, int tabRows){
  const int b  = blockIdx.x;
  const int sl = b & 7;
  const int rb = b >> 3;
  const int wv = threadIdx.x >> 6;
  const int lane = threadIdx.x & 63;
  const int row = rb * 4 + wv;
  if (row >= nrows) return;
  const int g = lane / 20;          // 0..2 active, g==3 (lanes 60-63) idle
  const int c = lane - g * 20;
  const bool act = g < 3;
  const int s = rp[row], e = rp[row + 1];
  const uint* base = T + ((size_t)sl * tabRows) * 20 + c;
  float aL0 = 0.f, aH0 = 0.f, aL1 = 0.f, aH1 = 0.f;
  if (act){
    int k = s + g;
    for (; k + 3 < e; k += 6){
      int   c0 = cs[k],  c1 = cs[k + 3];
      float v0 = vs[k],  v1 = vs[k + 3];
      uint  u0 = base[(size_t)c0 * 20];
      uint  u1 = base[(size_t)c1 * 20];
      aL0 = fmaf(v0, b2f_lo(u0), aL0); aH0 = fmaf(v0, b2f_hi(u0), aH0);
      aL1 = fmaf(v1, b2f_lo(u1), aL1); aH1 = fmaf(v1, b2f_hi(u1), aH1);
    }
    if (k < e){
      int c0 = cs[k]; float v0 = vs[k];
      uint u0 = base[(size_t)c0 * 20];
      aL0 = fmaf(v0, b2f_lo(u0), aL0); aH0 = fmaf(v0, b2f_hi(u0), aH0);
    }
  }
  float aL = aL0 + aL1, aH = aH0 + aH1;
  float tL1 = __shfl(aL, lane + 20);
  float tL2 = __shfl(aL, lane + 40);
  float tH1 = __shfl(aH, lane + 20);
  float tH2 = __shfl(aH, lane + 40);
  aL += tL1 + tL2;
  aH += tH1 + tH2;
  if (lane < 20)
    O[(size_t)row * PD_U + sl * 20 + lane] = packb(aL, aH);
}

// ---------------- MFMA GEMM: C = act(A[M,320]bf16 @ B[n][k]bf16^T) ----------------
// BM=128, BN=160, BK=64, 4 waves (2x2), wave tile 64x80 (4x5 16x16 frags).
// slcRows>0: write C slice-major [8][slcRows][40]; else row-major with stride ldc.
__global__ __launch_bounds__(256) void k_mgemm(const ushort* __restrict__ A, const ushort* __restrict__ B,
        const float* __restrict__ bias, const float* __restrict__ bng, const float* __restrict__ bnb,
        ushort* __restrict__ C, int M, int Nvalid, int ldc, int relu, int slcRows){
  __shared__ ushort As[128][72];
  __shared__ ushort Bs[160][72];
  const int t = threadIdx.x;
  const int wid = t >> 6, lane = t & 63;
  const int bm = blockIdx.y << 7;
  const int bn = blockIdx.x * 160;
  const int wm = (wid >> 1) << 6;   // 0 / 64
  const int wn = (wid & 1) * 80;    // 0 / 80
  const int r16 = lane & 15;
  const int h8 = (lane >> 4) << 3;  // k-offset within 32
  f32x4 acc[4][5] = {};
  for (int k0 = 0; k0 < PD; k0 += 64){
    #pragma unroll
    for (int i = 0; i < 4; ++i){
      int q = t + (i << 8);
      int r = q >> 3, c = (q & 7) << 3;
      int gm = bm + r; if (gm >= M) gm = M - 1;
      *(bf16x8*)(&As[r][c]) = *(const bf16x8*)(A + (size_t)gm * PD + k0 + c);
    }
    #pragma unroll
    for (int i = 0; i < 5; ++i){
      int q = t + (i << 8);
      int r = q >> 3, c = (q & 7) << 3;
      *(bf16x8*)(&Bs[r][c]) = *(const bf16x8*)(B + (size_t)(bn + r) * PD + k0 + c);
    }
    __syncthreads();
    #pragma unroll
    for (int kk = 0; kk < 2; ++kk){
      bf16x8 af[4], bfr[5];
      #pragma unroll
      for (int m = 0; m < 4; ++m)
        af[m] = *(const bf16x8*)(&As[wm + m * 16 + r16][kk * 32 + h8]);
      #pragma unroll
      for (int n = 0; n < 5; ++n)
        bfr[n] = *(const bf16x8*)(&Bs[wn + n * 16 + r16][kk * 32 + h8]);
      #pragma unroll
      for (int m = 0; m < 4; ++m)
        #pragma unroll
        for (int n = 0; n < 5; ++n)
          acc[m][n] = __builtin_amdgcn_mfma_f32_16x16x32_bf16(af[m], bfr[n], acc[m][n], 0, 0, 0);
    }
    __syncthreads();
  }
  const int cr = (lane >> 4) << 2;
  #pragma unroll
  for (int m = 0; m < 4; ++m){
    #pragma unroll
    for (int n = 0; n < 5; ++n){
      int col = bn + wn + n * 16 + r16;
      #pragma unroll
      for (int j = 0; j < 4; ++j){
        int row = bm + wm + m * 16 + cr + j;
        if (row >= M) continue;
        float v = acc[m][n][j];
        if (col < Nvalid){
          if (bias) v += bias[col];
          if (bng)  v = v * (bng[col] * BN_SCALE) + bnb[col];
          if (relu) v = fmaxf(v, 0.f);
        } else v = 0.f;
        if (slcRows > 0){
          int sl2 = col / 40, cc = col % 40;
          C[((size_t)sl2 * slcRows + row) * 40 + cc] = f2b(v);
        } else {
          C[(size_t)row * ldc + col] = f2b(v);
        }
      }
    }
  }
}

// ---------------- residual + LayerNorm; S = LN(0.3*emb + 0.7*H) + emb ----------------
// Hb and S are slice-major uint tables [8][NW][20].
__global__ __launch_bounds__(64) void k_res_ln(const float* __restrict__ emb, const uint* __restrict__ Hb,
        const float* __restrict__ g, const float* __restrict__ bb, uint* __restrict__ S){
  int row = blockIdx.x, lane = threadIdx.x;
  const float* e = emb + (size_t)row * DIM;
  float x[6], ev[6];
  float sum = 0.f, sq = 0.f;
  #pragma unroll
  for (int j = 0; j < 3; ++j){
    int i = lane + j * 64;
    float e0 = 0.f, e1 = 0.f, h0 = 0.f, h1 = 0.f;
    if (i < 150){
      uint u = Hb[((size_t)(i / 20) * NW + row) * 20 + (i % 20)];
      h0 = b2f_lo(u); h1 = b2f_hi(u);
      e0 = e[2 * i]; e1 = e[2 * i + 1];
    }
    float v0 = 0.3f * e0 + 0.7f * h0;
    float v1 = 0.3f * e1 + 0.7f * h1;
    if (i >= 150){ v0 = 0.f; v1 = 0.f; }
    x[2*j] = v0; x[2*j+1] = v1; ev[2*j] = e0; ev[2*j+1] = e1;
    sum += v0 + v1; sq += v0 * v0 + v1 * v1;
  }
  #pragma unroll
  for (int o = 32; o > 0; o >>= 1){ sum += __shfl_down(sum, o); sq += __shfl_down(sq, o); }
  sum = __shfl(sum, 0); sq = __shfl(sq, 0);
  const float inv = 1.f / (float)DIM;
  float mu = sum * inv;
  float var = sq * inv - mu * mu;
  float rs = rsqrtf(var + 1e-5f);
  #pragma unroll
  for (int j = 0; j < 3; ++j){
    int i = lane + j * 64;
    if (i >= PD_U) continue;
    uint w = 0;
    if (i < 150){
      float r0 = (x[2*j]   - mu) * rs * g[2*i]   + bb[2*i]   + ev[2*j];
      float r1 = (x[2*j+1] - mu) * rs * g[2*i+1] + bb[2*i+1] + ev[2*j+1];
      w = packb(r0, r1);
    }
    S[((size_t)(i / 20) * NW + row) * 20 + (i % 20)] = w;
  }
}

// ---------------- classifier: [ND,150]bf16 @ [2,150]^T + b -> fp32 out ----------------
__global__ void k_clf(const uint* __restrict__ h2, const float* __restrict__ w,
                      const float* __restrict__ bias, float* __restrict__ out){
  int m = blockIdx.x * blockDim.x + threadIdx.x;
  if (m >= ND) return;
  const uint* hr = h2 + (size_t)m * 80;
  float s0 = bias[0], s1 = bias[1];
  #pragma unroll 5
  for (int i = 0; i < 75; ++i){
    uint u = hr[i];
    float h0 = b2f_lo(u), h1 = b2f_hi(u);
    int k = 2 * i;
    s0 = fmaf(h0, w[k], fmaf(h1, w[k + 1], s0));
    s1 = fmaf(h0, w[DIM2 + k], fmaf(h1, w[DIM2 + k + 1], s1));
  }
  out[m * 2] = s0;
  out[m * 2 + 1] = s1;
}

extern "C" void kernel_launch(void* const* d_in, const int* in_sizes, int n_in,
                              void* d_out, int out_size, void* d_ws, size_t ws_size,
                              hipStream_t stream){
  const int*   a_rows = (const int*)  d_in[0];
  const int*   a_cols = (const int*)  d_in[1];
  const float* a_vals = (const float*)d_in[2];
  const int*   x_rows = (const int*)  d_in[3];
  const int*   x_cols = (const int*)  d_in[4];
  const float* x_vals = (const float*)d_in[5];
  const float* emb    = (const float*)d_in[6];
  const float* w1     = (const float*)d_in[7];
  const float* w2     = (const float*)d_in[8];
  const float* w3     = (const float*)d_in[9];
  const float* ln_g   = (const float*)d_in[10];
  const float* ln_b   = (const float*)d_in[11];
  const float* m_w1   = (const float*)d_in[12];
  const float* m_b1   = (const float*)d_in[13];
  const float* bn1_g  = (const float*)d_in[14];
  const float* bn1_b  = (const float*)d_in[15];
  const float* m_w2   = (const float*)d_in[16];
  const float* m_b2   = (const float*)d_in[17];
  const float* bn2_g  = (const float*)d_in[18];
  const float* bn2_b  = (const float*)d_in[19];
  const float* clf_w  = (const float*)d_in[20];
  const float* clf_b  = (const float*)d_in[21];
  float* out = (float*)d_out;

  char* ws = (char*)d_ws;
  size_t off = 0;
  auto take = [&](size_t nbytes)->void*{
    void* p = ws + off;
    off += (nbytes + 255) & ~(size_t)255;
    return p;
  };
  int*    a_rp   = (int*)   take((NW + 1) * 4);
  int*    a_cs   = (int*)   take((size_t)NNZA * 4);
  float*  a_vs   = (float*) take((size_t)NNZA * 4);
  int*    x_rp   = (int*)   take((ND + 1) * 4);
  int*    x_cs   = (int*)   take((size_t)NNZX * 4);
  float*  x_vs   = (float*) take((size_t)NNZX * 4);
  int*    cursor = (int*)   take((size_t)NW * 4);
  int*    bsums  = (int*)   take(64 * 4);
  ushort* embb   = (ushort*)take((size_t)NW * PD * 2);   // slice-major
  ushort* Tb     = (ushort*)take((size_t)NW * PD * 2);   // spmm out (row-major) / res_ln out (slice-major)
  ushort* Hb     = (ushort*)take((size_t)NW * PD * 2);   // mgemm out (slice-major) / doc bufs
  ushort* w1b    = (ushort*)take((size_t)PD * PD * 2);
  ushort* w2b    = (ushort*)take((size_t)PD * PD * 2);
  ushort* w3b    = (ushort*)take((size_t)PD * PD * 2);
  ushort* mw1b   = (ushort*)take((size_t)PD * PD * 2);
  ushort* mw2b   = (ushort*)take((size_t)PD * PD * 2);
  // doc-stage buffers alias Hb (slice-major word-H is dead after res_ln)
  ushort* docHb = Hb;
  ushort* h1b   = Hb + (size_t)ND * PD;
  ushort* h2b   = Hb + (size_t)2 * ND * PD;  // stride 160

  // ---- CSR build for A ----
  int nbA = cdiv(NW, 1024);
  hipMemsetAsync(cursor, 0, NW * 4, stream);
  k_hist<<<cdiv(NNZA, 256), 256, 0, stream>>>(a_rows, NNZA, cursor);
  k_bsum<<<nbA, 1024, 0, stream>>>(cursor, NW, bsums);
  k_scan_small<<<1, 64, 0, stream>>>(bsums, nbA, a_rp, NW);
  k_scan_apply<<<nbA, 1024, 0, stream>>>(cursor, NW, bsums, a_rp);
  k_copy_int<<<cdiv(NW, 256), 256, 0, stream>>>(a_rp, cursor, NW);
  k_scatter<<<cdiv(NNZA, 256), 256, 0, stream>>>(a_rows, a_cols, a_vals, NNZA, cursor, a_cs, a_vs);
  // ---- CSR build for X ----
  int nbX = cdiv(ND, 1024);
  hipMemsetAsync(cursor, 0, ND * 4, stream);
  k_hist<<<cdiv(NNZX, 256), 256, 0, stream>>>(x_rows, NNZX, cursor);
  k_bsum<<<nbX, 1024, 0, stream>>>(cursor, ND, bsums);
  k_scan_small<<<1, 64, 0, stream>>>(bsums, nbX, x_rp, ND);
  k_scan_apply<<<nbX, 1024, 0, stream>>>(cursor, ND, bsums, x_rp);
  k_copy_int<<<cdiv(ND, 256), 256, 0, stream>>>(x_rp, cursor, ND);
  k_scatter<<<cdiv(NNZX, 256), 256, 0, stream>>>(x_rows, x_cols, x_vals, NNZX, cursor, x_cs, x_vs);

  // ---- fp32 -> bf16 padded conversions ----
  k_f2b_pad8<<<cdiv(NW * 40, 256), 256, 0, stream>>>(emb, embb, NW, DIM, NW, PD, NW);   // slice-major
  k_f2b_pad8<<<cdiv(PD * 40, 256), 256, 0, stream>>>(w1, w1b, DIM, DIM, PD, PD, 0);
  k_f2b_pad8<<<cdiv(PD * 40, 256), 256, 0, stream>>>(w2, w2b, DIM, DIM, PD, PD, 0);
  k_f2b_pad8<<<cdiv(PD * 40, 256), 256, 0, stream>>>(w3, w3b, DIM, DIM, PD, PD, 0);
  k_f2b_pad8<<<cdiv(PD * 40, 256), 256, 0, stream>>>(m_w1, mw1b, DIM, DIM, PD, PD, 0);
  k_f2b_pad8<<<cdiv(PD * 40, 256), 256, 0, stream>>>(m_w2, mw2b, DIM2, DIM, PD, PD, 0);

  // ---- word GCN ----
  int gsA = cdiv(NW, 4) * 8;
  int gsX = cdiv(ND, 4) * 8;
  dim3 gg(2, cdiv(NW, 128));
  k_spmm_s2<<<gsA, 256, 0, stream>>>(a_rp, a_cs, a_vs, (const uint*)embb, (uint*)Tb, NW, NW);
  k_mgemm<<<gg, 256, 0, stream>>>(Tb, w1b, nullptr, nullptr, nullptr, Hb, NW, DIM, PD, 1, NW);
  k_spmm_s2<<<gsA, 256, 0, stream>>>(a_rp, a_cs, a_vs, (const uint*)Hb, (uint*)Tb, NW, NW);
  k_mgemm<<<gg, 256, 0, stream>>>(Tb, w2b, nullptr, nullptr, nullptr, Hb, NW, DIM, PD, 1, NW);
  k_spmm_s2<<<gsA, 256, 0, stream>>>(a_rp, a_cs, a_vs, (const uint*)Hb, (uint*)Tb, NW, NW);
  k_mgemm<<<gg, 256, 0, stream>>>(Tb, w3b, nullptr, nullptr, nullptr, Hb, NW, DIM, PD, 1, NW);
  // ---- residual + LN (slice-major in Hb -> slice-major S in Tb) ----
  k_res_ln<<<NW, 64, 0, stream>>>(emb, (const uint*)Hb, ln_g, ln_b, (uint*)Tb);
  // ---- doc aggregation (sliced SpMM over summed matrix; row-major out) ----
  k_spmm_s2<<<gsX, 256, 0, stream>>>(x_rp, x_cs, x_vs, (const uint*)Tb, (uint*)docHb, ND, NW);
  // ---- MLP head (row-major) ----
  dim3 g1(2, cdiv(ND, 128));
  k_mgemm<<<g1, 256, 0, stream>>>(docHb, mw1b, m_b1, bn1_g, bn1_b, h1b, ND, DIM, PD, 1, 0);
  dim3 g2(1, cdiv(ND, 128));
  k_mgemm<<<g2, 256, 0, stream>>>(h1b, mw2b, m_b2, bn2_g, bn2_b, h2b, ND, DIM2, 160, 1, 0);
  k_clf<<<cdiv(ND, 256), 256, 0, stream>>>((const uint*)h2b, clf_w, clf_b, out);
}

// Round 7
// 647.189 us; speedup vs baseline: 1.4228x; 1.0598x over previous
//
#include <hip/hip_runtime.h>

#define NW 30000
#define ND 8192
#define DIM 300
#define DIM2 150
#define NNZA 600000
#define NNZX 524288
#define PD 320            // padded feature stride (bf16 elems)
#define PD_U 160          // padded stride in uint (2 bf16 each)
#define BN_SCALE 0.99999500003749971f

typedef unsigned int uint;
typedef unsigned short ushort;
typedef __attribute__((ext_vector_type(8))) short bf16x8;
typedef __attribute__((ext_vector_type(4))) float f32x4;
typedef __attribute__((ext_vector_type(4))) uint uint4v;
typedef __attribute__((ext_vector_type(2))) uint uint2v;

static inline int cdiv(int a, int b){ return (a + b - 1) / b; }

__device__ __forceinline__ float b2f_lo(uint u){ return __builtin_bit_cast(float, u << 16); }
__device__ __forceinline__ float b2f_hi(uint u){ return __builtin_bit_cast(float, u & 0xffff0000u); }
__device__ __forceinline__ ushort f2b(float f){
  uint u = __builtin_bit_cast(uint, f);
  u += 0x7fffu + ((u >> 16) & 1u);
  return (ushort)(u >> 16);
}
__device__ __forceinline__ uint packb(float x, float y){
  return (uint)f2b(x) | ((uint)f2b(y) << 16);
}

// ---------------- CSR build ----------------
__global__ void k_hist(const int* __restrict__ rows, int n, int* __restrict__ cnt){
  int i = blockIdx.x * blockDim.x + threadIdx.x;
  if (i < n) atomicAdd(&cnt[rows[i]], 1);
}

__global__ void k_copy_int(const int* __restrict__ a, int* __restrict__ b, int n){
  int i = blockIdx.x * blockDim.x + threadIdx.x;
  if (i < n) b[i] = a[i];
}

// hierarchical scan: (1) per-1024-block sums
__global__ __launch_bounds__(1024) void k_bsum(const int* __restrict__ cnt, int n, int* __restrict__ bs){
  __shared__ int sd[1024];
  int t = threadIdx.x;
  int i = blockIdx.x * 1024 + t;
  sd[t] = (i < n) ? cnt[i] : 0;
  __syncthreads();
  #pragma unroll
  for (int o = 512; o > 0; o >>= 1){
    if (t < o) sd[t] += sd[t + o];
    __syncthreads();
  }
  if (t == 0) bs[blockIdx.x] = sd[0];
}

// (2) single-wave exclusive scan of block sums (nb <= 64), writes total to rp[n]
__global__ __launch_bounds__(64) void k_scan_small(int* __restrict__ bs, int nb,
                                                   int* __restrict__ rp, int n){
  int t = threadIdx.x;
  int orig = (t < nb) ? bs[t] : 0;
  int v = orig;
  #pragma unroll
  for (int o = 1; o < 64; o <<= 1){
    int x = __shfl_up(v, o);
    if (t >= o) v += x;
  }
  if (t < nb) bs[t] = v - orig;
  if (t == nb - 1) rp[n] = v;
}

// (3) per-block scan + offset
__global__ __launch_bounds__(1024) void k_scan_apply(const int* __restrict__ cnt, int n,
        const int* __restrict__ bs, int* __restrict__ rp){
  __shared__ int sd[1024];
  int t = threadIdx.x;
  int i = blockIdx.x * 1024 + t;
  int v = (i < n) ? cnt[i] : 0;
  sd[t] = v;
  __syncthreads();
  for (int o = 1; o < 1024; o <<= 1){
    int x = (t >= o) ? sd[t - o] : 0;
    __syncthreads();
    sd[t] += x;
    __syncthreads();
  }
  if (i < n) rp[i] = bs[blockIdx.x] + sd[t] - v;
}

__global__ void k_scatter(const int* __restrict__ rows, const int* __restrict__ cols,
                          const float* __restrict__ vals, int n, int* __restrict__ cursor,
                          int* __restrict__ cs, float* __restrict__ vs){
  int i = blockIdx.x * blockDim.x + threadIdx.x;
  if (i < n){
    int r = rows[i];
    int p = atomicAdd(&cursor[r], 1);
    cs[p] = cols[i];
    vs[p] = vals[i];
  }
}

// ---------------- fp32 -> bf16 pad-convert, 8 cols/thread, uint4 stores ----------------
// slcRows>0: write slice-major T[sl][slcRows][40] (sl = col/40)
__global__ void k_f2b_pad8(const float* __restrict__ src, ushort* __restrict__ dst,
                           int srows, int scols, int drows, int dstride, int slcRows){
  int q = blockIdx.x * blockDim.x + threadIdx.x;   // one q = 8 output cols
  int perRow = dstride >> 3;
  int r = q / perRow;
  int c = (q - r * perRow) << 3;
  if (r >= drows) return;
  float x[8];
  #pragma unroll
  for (int j = 0; j < 8; ++j)
    x[j] = (r < srows && c + j < scols) ? src[(size_t)r * scols + c + j] : 0.f;
  uint4v o;
  o.x = packb(x[0], x[1]); o.y = packb(x[2], x[3]);
  o.z = packb(x[4], x[5]); o.w = packb(x[6], x[7]);
  if (slcRows > 0){
    int sl = c / 40, cc = c % 40;
    *(uint4v*)(dst + ((size_t)sl * slcRows + r) * 40 + cc) = o;
  } else {
    *(uint4v*)(dst + (size_t)r * dstride + c) = o;
  }
}

// ---------------- XCD-sliced SpMM, slice-major table, uint2 gathers ----------------
// blockIdx.x = rb*8 + sl -> slice sl pinned to XCD sl (HW round-robin). Slice = tabRows*80 B,
// L2-resident (2.4 MB @ NW). One row per wave; 6 nnz in parallel via 6 groups x 10 lanes
// (uint2 = 8 B/lane); unroll-2 -> 2 gather chains in flight. Output O row-major [nrows][PD_U].
__global__ __launch_bounds__(256) void k_spmm_s3(const int* __restrict__ rp, const int* __restrict__ cs,
        const float* __restrict__ vs, const uint2v* __restrict__ T2, uint* __restrict__ O,
        int nrows, int tabRows){
  const int b  = blockIdx.x;
  const int sl = b & 7;
  const int rb = b >> 3;
  const int wv = threadIdx.x >> 6;
  const int lane = threadIdx.x & 63;
  const int row = rb * 4 + wv;
  if (row >= nrows) return;
  const int g = lane / 10;          // 0..5 active, g==6 (lanes 60-63) idle
  const int p = lane - g * 10;
  const bool act = g < 6;
  const int s = rp[row], e = rp[row + 1];
  const uint2v* base = T2 + (size_t)sl * tabRows * 10 + p;
  float xL0=0,xH0=0,yL0=0,yH0=0;
  float xL1=0,xH1=0,yL1=0,yH1=0;
  if (act){
    int k = s + g;
    for (; k + 6 < e; k += 12){
      int   c0 = cs[k],     c1 = cs[k + 6];
      float v0 = vs[k],     v1 = vs[k + 6];
      uint2v u0 = base[c0 * 10];
      uint2v u1 = base[c1 * 10];
      xL0 = fmaf(v0, b2f_lo(u0.x), xL0); xH0 = fmaf(v0, b2f_hi(u0.x), xH0);
      yL0 = fmaf(v0, b2f_lo(u0.y), yL0); yH0 = fmaf(v0, b2f_hi(u0.y), yH0);
      xL1 = fmaf(v1, b2f_lo(u1.x), xL1); xH1 = fmaf(v1, b2f_hi(u1.x), xH1);
      yL1 = fmaf(v1, b2f_lo(u1.y), yL1); yH1 = fmaf(v1, b2f_hi(u1.y), yH1);
    }
    if (k < e){
      int c0 = cs[k]; float v0 = vs[k];
      uint2v u0 = base[c0 * 10];
      xL0 = fmaf(v0, b2f_lo(u0.x), xL0); xH0 = fmaf(v0, b2f_hi(u0.x), xH0);
      yL0 = fmaf(v0, b2f_lo(u0.y), yL0); yH0 = fmaf(v0, b2f_hi(u0.y), yH0);
    }
  }
  float xL = xL0 + xL1, xH = xH0 + xH1, yL = yL0 + yL1, yH = yH0 + yH1;
  // reduce across the 6 groups: lanes<30 fold +30, then lanes<10 fold +10,+20
  float t;
  t = __shfl(xL, lane + 30); if (lane < 30) xL += t;
  t = __shfl(xH, lane + 30); if (lane < 30) xH += t;
  t = __shfl(yL, lane + 30); if (lane < 30) yL += t;
  t = __shfl(yH, lane + 30); if (lane < 30) yH += t;
  float t1, t2;
  t1 = __shfl(xL, lane + 10); t2 = __shfl(xL, lane + 20); xL += t1 + t2;
  t1 = __shfl(xH, lane + 10); t2 = __shfl(xH, lane + 20); xH += t1 + t2;
  t1 = __shfl(yL, lane + 10); t2 = __shfl(yL, lane + 20); yL += t1 + t2;
  t1 = __shfl(yH, lane + 10); t2 = __shfl(yH, lane + 20); yH += t1 + t2;
  if (lane < 10){
    uint2v o;
    o.x = packb(xL, xH);
    o.y = packb(yL, yH);
    *(uint2v*)(O + (size_t)row * PD_U + sl * 20 + 2 * p) = o;
  }
}

// ---------------- MFMA GEMM: C = act(A[M,320]bf16 @ B[n][k]bf16^T) ----------------
// BM=128, BN=160, BK=64, 4 waves (2x2), wave tile 64x80 (4x5 16x16 frags).
// slcRows>0: write C slice-major [8][slcRows][40]; else row-major with stride ldc.
__global__ __launch_bounds__(256) void k_mgemm(const ushort* __restrict__ A, const ushort* __restrict__ B,
        const float* __restrict__ bias, const float* __restrict__ bng, const float* __restrict__ bnb,
        ushort* __restrict__ C, int M, int Nvalid, int ldc, int relu, int slcRows){
  __shared__ ushort As[128][72];
  __shared__ ushort Bs[160][72];
  const int t = threadIdx.x;
  const int wid = t >> 6, lane = t & 63;
  const int bm = blockIdx.y << 7;
  const int bn = blockIdx.x * 160;
  const int wm = (wid >> 1) << 6;   // 0 / 64
  const int wn = (wid & 1) * 80;    // 0 / 80
  const int r16 = lane & 15;
  const int h8 = (lane >> 4) << 3;  // k-offset within 32
  f32x4 acc[4][5] = {};
  for (int k0 = 0; k0 < PD; k0 += 64){
    #pragma unroll
    for (int i = 0; i < 4; ++i){
      int q = t + (i << 8);
      int r = q >> 3, c = (q & 7) << 3;
      int gm = bm + r; if (gm >= M) gm = M - 1;
      *(bf16x8*)(&As[r][c]) = *(const bf16x8*)(A + (size_t)gm * PD + k0 + c);
    }
    #pragma unroll
    for (int i = 0; i < 5; ++i){
      int q = t + (i << 8);
      int r = q >> 3, c = (q & 7) << 3;
      *(bf16x8*)(&Bs[r][c]) = *(const bf16x8*)(B + (size_t)(bn + r) * PD + k0 + c);
    }
    __syncthreads();
    #pragma unroll
    for (int kk = 0; kk < 2; ++kk){
      bf16x8 af[4], bfr[5];
      #pragma unroll
      for (int m = 0; m < 4; ++m)
        af[m] = *(const bf16x8*)(&As[wm + m * 16 + r16][kk * 32 + h8]);
      #pragma unroll
      for (int n = 0; n < 5; ++n)
        bfr[n] = *(const bf16x8*)(&Bs[wn + n * 16 + r16][kk * 32 + h8]);
      #pragma unroll
      for (int m = 0; m < 4; ++m)
        #pragma unroll
        for (int n = 0; n < 5; ++n)
          acc[m][n] = __builtin_amdgcn_mfma_f32_16x16x32_bf16(af[m], bfr[n], acc[m][n], 0, 0, 0);
    }
    __syncthreads();
  }
  const int cr = (lane >> 4) << 2;
  #pragma unroll
  for (int m = 0; m < 4; ++m){
    #pragma unroll
    for (int n = 0; n < 5; ++n){
      int col = bn + wn + n * 16 + r16;
      #pragma unroll
      for (int j = 0; j < 4; ++j){
        int row = bm + wm + m * 16 + cr + j;
        if (row >= M) continue;
        float v = acc[m][n][j];
        if (col < Nvalid){
          if (bias) v += bias[col];
          if (bng)  v = v * (bng[col] * BN_SCALE) + bnb[col];
          if (relu) v = fmaxf(v, 0.f);
        } else v = 0.f;
        if (slcRows > 0){
          int sl2 = col / 40, cc = col % 40;
          C[((size_t)sl2 * slcRows + row) * 40 + cc] = f2b(v);
        } else {
          C[(size_t)row * ldc + col] = f2b(v);
        }
      }
    }
  }
}

// ---------------- residual + LayerNorm; S = LN(0.3*emb + 0.7*H) + emb ----------------
// Hb and S are slice-major uint tables [8][NW][20]. 4 rows/block (wave per row).
__global__ __launch_bounds__(256) void k_res_ln(const float* __restrict__ emb, const uint* __restrict__ Hb,
        const float* __restrict__ g, const float* __restrict__ bb, uint* __restrict__ S){
  int row = blockIdx.x * 4 + (threadIdx.x >> 6);
  int lane = threadIdx.x & 63;
  if (row >= NW) return;
  const float* e = emb + (size_t)row * DIM;
  float x[6], ev[6];
  float sum = 0.f, sq = 0.f;
  #pragma unroll
  for (int j = 0; j < 3; ++j){
    int i = lane + j * 64;
    float e0 = 0.f, e1 = 0.f, h0 = 0.f, h1 = 0.f;
    if (i < 150){
      uint u = Hb[((size_t)(i / 20) * NW + row) * 20 + (i % 20)];
      h0 = b2f_lo(u); h1 = b2f_hi(u);
      e0 = e[2 * i]; e1 = e[2 * i + 1];
    }
    float v0 = 0.3f * e0 + 0.7f * h0;
    float v1 = 0.3f * e1 + 0.7f * h1;
    if (i >= 150){ v0 = 0.f; v1 = 0.f; }
    x[2*j] = v0; x[2*j+1] = v1; ev[2*j] = e0; ev[2*j+1] = e1;
    sum += v0 + v1; sq += v0 * v0 + v1 * v1;
  }
  #pragma unroll
  for (int o = 32; o > 0; o >>= 1){ sum += __shfl_down(sum, o); sq += __shfl_down(sq, o); }
  sum = __shfl(sum, 0); sq = __shfl(sq, 0);
  const float inv = 1.f / (float)DIM;
  float mu = sum * inv;
  float var = sq * inv - mu * mu;
  float rs = rsqrtf(var + 1e-5f);
  #pragma unroll
  for (int j = 0; j < 3; ++j){
    int i = lane + j * 64;
    if (i >= PD_U) continue;
    uint w = 0;
    if (i < 150){
      float r0 = (x[2*j]   - mu) * rs * g[2*i]   + bb[2*i]   + ev[2*j];
      float r1 = (x[2*j+1] - mu) * rs * g[2*i+1] + bb[2*i+1] + ev[2*j+1];
      w = packb(r0, r1);
    }
    S[((size_t)(i / 20) * NW + row) * 20 + (i % 20)] = w;
  }
}

// ---------------- classifier: [ND,150]bf16 @ [2,150]^T + b -> fp32 out ----------------
__global__ void k_clf(const uint* __restrict__ h2, const float* __restrict__ w,
                      const float* __restrict__ bias, float* __restrict__ out){
  int m = blockIdx.x * blockDim.x + threadIdx.x;
  if (m >= ND) return;
  const uint* hr = h2 + (size_t)m * 80;
  float s0 = bias[0], s1 = bias[1];
  #pragma unroll 5
  for (int i = 0; i < 75; ++i){
    uint u = hr[i];
    float h0 = b2f_lo(u), h1 = b2f_hi(u);
    int k = 2 * i;
    s0 = fmaf(h0, w[k], fmaf(h1, w[k + 1], s0));
    s1 = fmaf(h0, w[DIM2 + k], fmaf(h1, w[DIM2 + k + 1], s1));
  }
  out[m * 2] = s0;
  out[m * 2 + 1] = s1;
}

extern "C" void kernel_launch(void* const* d_in, const int* in_sizes, int n_in,
                              void* d_out, int out_size, void* d_ws, size_t ws_size,
                              hipStream_t stream){
  const int*   a_rows = (const int*)  d_in[0];
  const int*   a_cols = (const int*)  d_in[1];
  const float* a_vals = (const float*)d_in[2];
  const int*   x_rows = (const int*)  d_in[3];
  const int*   x_cols = (const int*)  d_in[4];
  const float* x_vals = (const float*)d_in[5];
  const float* emb    = (const float*)d_in[6];
  const float* w1     = (const float*)d_in[7];
  const float* w2     = (const float*)d_in[8];
  const float* w3     = (const float*)d_in[9];
  const float* ln_g   = (const float*)d_in[10];
  const float* ln_b   = (const float*)d_in[11];
  const float* m_w1   = (const float*)d_in[12];
  const float* m_b1   = (const float*)d_in[13];
  const float* bn1_g  = (const float*)d_in[14];
  const float* bn1_b  = (const float*)d_in[15];
  const float* m_w2   = (const float*)d_in[16];
  const float* m_b2   = (const float*)d_in[17];
  const float* bn2_g  = (const float*)d_in[18];
  const float* bn2_b  = (const float*)d_in[19];
  const float* clf_w  = (const float*)d_in[20];
  const float* clf_b  = (const float*)d_in[21];
  float* out = (float*)d_out;

  char* ws = (char*)d_ws;
  size_t off = 0;
  auto take = [&](size_t nbytes)->void*{
    void* p = ws + off;
    off += (nbytes + 255) & ~(size_t)255;
    return p;
  };
  int*    a_rp   = (int*)   take((NW + 1) * 4);
  int*    a_cs   = (int*)   take((size_t)NNZA * 4);
  float*  a_vs   = (float*) take((size_t)NNZA * 4);
  int*    x_rp   = (int*)   take((ND + 1) * 4);
  int*    x_cs   = (int*)   take((size_t)NNZX * 4);
  float*  x_vs   = (float*) take((size_t)NNZX * 4);
  int*    cursor = (int*)   take((size_t)NW * 4);
  int*    bsums  = (int*)   take(64 * 4);
  ushort* embb   = (ushort*)take((size_t)NW * PD * 2);   // slice-major
  ushort* Tb     = (ushort*)take((size_t)NW * PD * 2);   // spmm out (row-major) / res_ln out (slice-major)
  ushort* Hb     = (ushort*)take((size_t)NW * PD * 2);   // mgemm out (slice-major) / doc bufs
  ushort* w1b    = (ushort*)take((size_t)PD * PD * 2);
  ushort* w2b    = (ushort*)take((size_t)PD * PD * 2);
  ushort* w3b    = (ushort*)take((size_t)PD * PD * 2);
  ushort* mw1b   = (ushort*)take((size_t)PD * PD * 2);
  ushort* mw2b   = (ushort*)take((size_t)PD * PD * 2);
  // doc-stage buffers alias Hb (slice-major word-H is dead after res_ln)
  ushort* docHb = Hb;
  ushort* h1b   = Hb + (size_t)ND * PD;
  ushort* h2b   = Hb + (size_t)2 * ND * PD;  // stride 160

  // ---- CSR build for A ----
  int nbA = cdiv(NW, 1024);
  hipMemsetAsync(cursor, 0, NW * 4, stream);
  k_hist<<<cdiv(NNZA, 256), 256, 0, stream>>>(a_rows, NNZA, cursor);
  k_bsum<<<nbA, 1024, 0, stream>>>(cursor, NW, bsums);
  k_scan_small<<<1, 64, 0, stream>>>(bsums, nbA, a_rp, NW);
  k_scan_apply<<<nbA, 1024, 0, stream>>>(cursor, NW, bsums, a_rp);
  k_copy_int<<<cdiv(NW, 256), 256, 0, stream>>>(a_rp, cursor, NW);
  k_scatter<<<cdiv(NNZA, 256), 256, 0, stream>>>(a_rows, a_cols, a_vals, NNZA, cursor, a_cs, a_vs);
  // ---- CSR build for X ----
  int nbX = cdiv(ND, 1024);
  hipMemsetAsync(cursor, 0, ND * 4, stream);
  k_hist<<<cdiv(NNZX, 256), 256, 0, stream>>>(x_rows, NNZX, cursor);
  k_bsum<<<nbX, 1024, 0, stream>>>(cursor, ND, bsums);
  k_scan_small<<<1, 64, 0, stream>>>(bsums, nbX, x_rp, ND);
  k_scan_apply<<<nbX, 1024, 0, stream>>>(cursor, ND, bsums, x_rp);
  k_copy_int<<<cdiv(ND, 256), 256, 0, stream>>>(x_rp, cursor, ND);
  k_scatter<<<cdiv(NNZX, 256), 256, 0, stream>>>(x_rows, x_cols, x_vals, NNZX, cursor, x_cs, x_vs);

  // ---- fp32 -> bf16 padded conversions ----
  k_f2b_pad8<<<cdiv(NW * 40, 256), 256, 0, stream>>>(emb, embb, NW, DIM, NW, PD, NW);   // slice-major
  k_f2b_pad8<<<cdiv(PD * 40, 256), 256, 0, stream>>>(w1, w1b, DIM, DIM, PD, PD, 0);
  k_f2b_pad8<<<cdiv(PD * 40, 256), 256, 0, stream>>>(w2, w2b, DIM, DIM, PD, PD, 0);
  k_f2b_pad8<<<cdiv(PD * 40, 256), 256, 0, stream>>>(w3, w3b, DIM, DIM, PD, PD, 0);
  k_f2b_pad8<<<cdiv(PD * 40, 256), 256, 0, stream>>>(m_w1, mw1b, DIM, DIM, PD, PD, 0);
  k_f2b_pad8<<<cdiv(PD * 40, 256), 256, 0, stream>>>(m_w2, mw2b, DIM2, DIM, PD, PD, 0);

  // ---- word GCN ----
  int gsA = cdiv(NW, 4) * 8;
  int gsX = cdiv(ND, 4) * 8;
  dim3 gg(2, cdiv(NW, 128));
  k_spmm_s3<<<gsA, 256, 0, stream>>>(a_rp, a_cs, a_vs, (const uint2v*)embb, (uint*)Tb, NW, NW);
  k_mgemm<<<gg, 256, 0, stream>>>(Tb, w1b, nullptr, nullptr, nullptr, Hb, NW, DIM, PD, 1, NW);
  k_spmm_s3<<<gsA, 256, 0, stream>>>(a_rp, a_cs, a_vs, (const uint2v*)Hb, (uint*)Tb, NW, NW);
  k_mgemm<<<gg, 256, 0, stream>>>(Tb, w2b, nullptr, nullptr, nullptr, Hb, NW, DIM, PD, 1, NW);
  k_spmm_s3<<<gsA, 256, 0, stream>>>(a_rp, a_cs, a_vs, (const uint2v*)Hb, (uint*)Tb, NW, NW);
  k_mgemm<<<gg, 256, 0, stream>>>(Tb, w3b, nullptr, nullptr, nullptr, Hb, NW, DIM, PD, 1, NW);
  // ---- residual + LN (slice-major in Hb -> slice-major S in Tb) ----
  k_res_ln<<<cdiv(NW, 4), 256, 0, stream>>>(emb, (const uint*)Hb, ln_g, ln_b, (uint*)Tb);
  // ---- doc aggregation (sliced SpMM over summed matrix; row-major out) ----
  k_spmm_s3<<<gsX, 256, 0, stream>>>(x_rp, x_cs, x_vs, (const uint2v*)Tb, (uint*)docHb, ND, NW);
  // ---- MLP head (row-major) ----
  dim3 g1(2, cdiv(ND, 128));
  k_mgemm<<<g1, 256, 0, stream>>>(docHb, mw1b, m_b1, bn1_g, bn1_b, h1b, ND, DIM, PD, 1, 0);
  dim3 g2(1, cdiv(ND, 128));
  k_mgemm<<<g2, 256, 0, stream>>>(h1b, mw2b, m_b2, bn2_g, bn2_b, h2b, ND, DIM2, 160, 1, 0);
  k_clf<<<cdiv(ND, 256), 256, 0, stream>>>((const uint*)h2b, clf_w, clf_b, out);
}

// Round 9
// 539.527 us; speedup vs baseline: 1.7067x; 1.1995x over previous
//
#include <hip/hip_runtime.h>

#define NW 30000
#define ND 8192
#define DIM 300
#define DIM2 150
#define NNZA 600000
#define NNZX 524288
#define PD 320            // padded feature stride (bf16 elems)
#define PD_U 160          // padded stride in uint (2 bf16 each)
#define BN_SCALE 0.99999500003749971f

typedef unsigned int uint;
typedef unsigned short ushort;
typedef __attribute__((ext_vector_type(8))) short bf16x8;
typedef __attribute__((ext_vector_type(4))) float f32x4;
typedef __attribute__((ext_vector_type(4))) uint uint4v;

static inline int cdiv(int a, int b){ return (a + b - 1) / b; }

__device__ __forceinline__ float b2f_lo(uint u){ return __builtin_bit_cast(float, u << 16); }
__device__ __forceinline__ float b2f_hi(uint u){ return __builtin_bit_cast(float, u & 0xffff0000u); }
__device__ __forceinline__ ushort f2b(float f){
  uint u = __builtin_bit_cast(uint, f);
  u += 0x7fffu + ((u >> 16) & 1u);
  return (ushort)(u >> 16);
}
__device__ __forceinline__ uint packb(float x, float y){
  return (uint)f2b(x) | ((uint)f2b(y) << 16);
}

// ---------------- CSR build ----------------
__global__ void k_hist(const int* __restrict__ rows, int n, int* __restrict__ cnt){
  int i = blockIdx.x * blockDim.x + threadIdx.x;
  if (i < n) atomicAdd(&cnt[rows[i]], 1);
}

// hierarchical scan: (1) per-1024-block sums
__global__ __launch_bounds__(1024) void k_bsum(const int* __restrict__ cnt, int n, int* __restrict__ bs){
  __shared__ int sd[1024];
  int t = threadIdx.x;
  int i = blockIdx.x * 1024 + t;
  sd[t] = (i < n) ? cnt[i] : 0;
  __syncthreads();
  #pragma unroll
  for (int o = 512; o > 0; o >>= 1){
    if (t < o) sd[t] += sd[t + o];
    __syncthreads();
  }
  if (t == 0) bs[blockIdx.x] = sd[0];
}

// (2) single-wave exclusive scan of block sums (nb <= 64), writes total to rp[n]
__global__ __launch_bounds__(64) void k_scan_small(int* __restrict__ bs, int nb,
                                                   int* __restrict__ rp, int n){
  int t = threadIdx.x;
  int orig = (t < nb) ? bs[t] : 0;
  int v = orig;
  #pragma unroll
  for (int o = 1; o < 64; o <<= 1){
    int x = __shfl_up(v, o);
    if (t >= o) v += x;
  }
  if (t < nb) bs[t] = v - orig;
  if (t == nb - 1) rp[n] = v;
}

// (3) per-block scan + offset; writes BOTH rp and the scatter cursor
__global__ __launch_bounds__(1024) void k_scan_apply(const int* __restrict__ cnt, int n,
        const int* __restrict__ bs, int* __restrict__ rp, int* __restrict__ cursor){
  __shared__ int sd[1024];
  int t = threadIdx.x;
  int i = blockIdx.x * 1024 + t;
  int v = (i < n) ? cnt[i] : 0;
  sd[t] = v;
  __syncthreads();
  for (int o = 1; o < 1024; o <<= 1){
    int x = (t >= o) ? sd[t - o] : 0;
    __syncthreads();
    sd[t] += x;
    __syncthreads();
  }
  if (i < n){
    int start = bs[blockIdx.x] + sd[t] - v;
    rp[i] = start;
    cursor[i] = start;
  }
}

__global__ void k_scatter(const int* __restrict__ rows, const int* __restrict__ cols,
                          const float* __restrict__ vals, int n, int* __restrict__ cursor,
                          int* __restrict__ cs, float* __restrict__ vs){
  int i = blockIdx.x * blockDim.x + threadIdx.x;
  if (i < n){
    int r = rows[i];
    int p = atomicAdd(&cursor[r], 1);
    cs[p] = cols[i];
    vs[p] = vals[i];
  }
}

// ---------------- fp32 -> bf16 pad-convert, 8 cols/thread, uint4 stores ----------------
__global__ void k_f2b_pad8(const float* __restrict__ src, ushort* __restrict__ dst,
                           int srows, int scols, int drows, int dstride){
  int q = blockIdx.x * blockDim.x + threadIdx.x;   // one q = 8 output cols
  int perRow = dstride >> 3;
  int r = q / perRow;
  int c = (q - r * perRow) << 3;
  if (r >= drows) return;
  float x[8];
  #pragma unroll
  for (int j = 0; j < 8; ++j)
    x[j] = (r < srows && c + j < scols) ? src[(size_t)r * scols + c + j] : 0.f;
  uint4v o;
  o.x = packb(x[0], x[1]); o.y = packb(x[2], x[3]);
  o.z = packb(x[4], x[5]); o.w = packb(x[6], x[7]);
  *(uint4v*)(dst + (size_t)r * dstride + c) = o;
}

// fused 5-weight convert: blockIdx.y selects the weight matrix
__global__ void k_f2b_w5(const float* __restrict__ w1, const float* __restrict__ w2,
                         const float* __restrict__ w3, const float* __restrict__ mw1,
                         const float* __restrict__ mw2,
                         ushort* __restrict__ d1, ushort* __restrict__ d2,
                         ushort* __restrict__ d3, ushort* __restrict__ d4,
                         ushort* __restrict__ d5){
  int q = blockIdx.x * blockDim.x + threadIdx.x;   // one q = 8 output cols
  int r = q / 40;
  int c = (q - r * 40) << 3;
  if (r >= PD) return;
  const float* src; ushort* dst; int srows;
  int wsel = blockIdx.y;
  if      (wsel == 0){ src = w1;  dst = d1; srows = DIM;  }
  else if (wsel == 1){ src = w2;  dst = d2; srows = DIM;  }
  else if (wsel == 2){ src = w3;  dst = d3; srows = DIM;  }
  else if (wsel == 3){ src = mw1; dst = d4; srows = DIM;  }
  else               { src = mw2; dst = d5; srows = DIM2; }
  float x[8];
  #pragma unroll
  for (int j = 0; j < 8; ++j)
    x[j] = (r < srows && c + j < DIM) ? src[(size_t)r * DIM + c + j] : 0.f;
  uint4v o;
  o.x = packb(x[0], x[1]); o.y = packb(x[2], x[3]);
  o.z = packb(x[4], x[5]); o.w = packb(x[6], x[7]);
  *(uint4v*)(dst + (size_t)r * PD + c) = o;
}

// ---------------- SpMM over bf16 table: one wave per row, unroll-4 (R4-proven) ----------------
__global__ __launch_bounds__(256) void k_spmm_b(const int* __restrict__ rp, const int* __restrict__ cs,
        const float* __restrict__ vs, const uint* __restrict__ Hb, uint* __restrict__ Ob, int nrows){
  int wid = (blockIdx.x * blockDim.x + threadIdx.x) >> 6;
  int lane = threadIdx.x & 63;
  if (wid >= nrows) return;
  int s = rp[wid], e = rp[wid + 1];
  const bool half = lane < 32;
  float acc[4][6] = {};
  int k = s;
  for (; k + 4 <= e; k += 4){
    #pragma unroll
    for (int j = 0; j < 4; ++j){
      int c = cs[k + j];
      float v = vs[k + j];
      const uint* p = Hb + (size_t)c * PD_U;
      uint u0 = p[lane], u1 = p[lane + 64];
      uint u2 = half ? p[lane + 128] : 0;
      acc[j][0] = fmaf(v, b2f_lo(u0), acc[j][0]);
      acc[j][1] = fmaf(v, b2f_hi(u0), acc[j][1]);
      acc[j][2] = fmaf(v, b2f_lo(u1), acc[j][2]);
      acc[j][3] = fmaf(v, b2f_hi(u1), acc[j][3]);
      acc[j][4] = fmaf(v, b2f_lo(u2), acc[j][4]);
      acc[j][5] = fmaf(v, b2f_hi(u2), acc[j][5]);
    }
  }
  for (; k < e; ++k){
    int c = cs[k];
    float v = vs[k];
    const uint* p = Hb + (size_t)c * PD_U;
    uint u0 = p[lane], u1 = p[lane + 64];
    uint u2 = half ? p[lane + 128] : 0;
    acc[0][0] = fmaf(v, b2f_lo(u0), acc[0][0]);
    acc[0][1] = fmaf(v, b2f_hi(u0), acc[0][1]);
    acc[0][2] = fmaf(v, b2f_lo(u1), acc[0][2]);
    acc[0][3] = fmaf(v, b2f_hi(u1), acc[0][3]);
    acc[0][4] = fmaf(v, b2f_lo(u2), acc[0][4]);
    acc[0][5] = fmaf(v, b2f_hi(u2), acc[0][5]);
  }
  #pragma unroll
  for (int d = 0; d < 6; ++d)
    acc[0][d] += (acc[1][d] + acc[2][d]) + acc[3][d];
  uint* o = Ob + (size_t)wid * PD_U;
  o[lane] = packb(acc[0][0], acc[0][1]);
  o[lane + 64] = packb(acc[0][2], acc[0][3]);
  if (half) o[lane + 128] = packb(acc[0][4], acc[0][5]);
}

// ---------------- MFMA GEMM: C[M,Nvalid] = act(A[M,320]bf16 @ B[n][k]bf16^T) (R4-proven) ------
// BM=128, BN=160, BK=64, 4 waves (2x2), wave tile 64x80 (4x5 16x16 frags).
__global__ __launch_bounds__(256) void k_mgemm(const ushort* __restrict__ A, const ushort* __restrict__ B,
        const float* __restrict__ bias, const float* __restrict__ bng, const float* __restrict__ bnb,
        ushort* __restrict__ C, int M, int Nvalid, int ldc, int relu){
  __shared__ ushort As[128][72];
  __shared__ ushort Bs[160][72];
  const int t = threadIdx.x;
  const int wid = t >> 6, lane = t & 63;
  const int bm = blockIdx.y << 7;
  const int bn = blockIdx.x * 160;
  const int wm = (wid >> 1) << 6;   // 0 / 64
  const int wn = (wid & 1) * 80;    // 0 / 80
  const int r16 = lane & 15;
  const int h8 = (lane >> 4) << 3;  // k-offset within 32
  f32x4 acc[4][5] = {};
  for (int k0 = 0; k0 < PD; k0 += 64){
    #pragma unroll
    for (int i = 0; i < 4; ++i){
      int q = t + (i << 8);
      int r = q >> 3, c = (q & 7) << 3;
      int gm = bm + r; if (gm >= M) gm = M - 1;
      *(bf16x8*)(&As[r][c]) = *(const bf16x8*)(A + (size_t)gm * PD + k0 + c);
    }
    #pragma unroll
    for (int i = 0; i < 5; ++i){
      int q = t + (i << 8);
      int r = q >> 3, c = (q & 7) << 3;
      *(bf16x8*)(&Bs[r][c]) = *(const bf16x8*)(B + (size_t)(bn + r) * PD + k0 + c);
    }
    __syncthreads();
    #pragma unroll
    for (int kk = 0; kk < 2; ++kk){
      bf16x8 af[4], bfr[5];
      #pragma unroll
      for (int m = 0; m < 4; ++m)
        af[m] = *(const bf16x8*)(&As[wm + m * 16 + r16][kk * 32 + h8]);
      #pragma unroll
      for (int n = 0; n < 5; ++n)
        bfr[n] = *(const bf16x8*)(&Bs[wn + n * 16 + r16][kk * 32 + h8]);
      #pragma unroll
      for (int m = 0; m < 4; ++m)
        #pragma unroll
        for (int n = 0; n < 5; ++n)
          acc[m][n] = __builtin_amdgcn_mfma_f32_16x16x32_bf16(af[m], bfr[n], acc[m][n], 0, 0, 0);
    }
    __syncthreads();
  }
  const int cr = (lane >> 4) << 2;
  #pragma unroll
  for (int m = 0; m < 4; ++m){
    #pragma unroll
    for (int n = 0; n < 5; ++n){
      int col = bn + wn + n * 16 + r16;
      #pragma unroll
      for (int j = 0; j < 4; ++j){
        int row = bm + wm + m * 16 + cr + j;
        if (row >= M) continue;
        float v = acc[m][n][j];
        if (col < Nvalid){
          if (bias) v += bias[col];
          if (bng)  v = v * (bng[col] * BN_SCALE) + bnb[col];
          if (relu) v = fmaxf(v, 0.f);
        } else v = 0.f;
        C[(size_t)row * ldc + col] = f2b(v);
      }
    }
  }
}

// ---------------- residual + LayerNorm; S = LN(0.3*emb + 0.7*H) + emb (row-major, 4 rows/block) --
__global__ __launch_bounds__(256) void k_res_ln(const float* __restrict__ emb, const uint* __restrict__ Hb,
        const float* __restrict__ g, const float* __restrict__ bb, uint* __restrict__ S){
  int row = blockIdx.x * 4 + (threadIdx.x >> 6);
  int lane = threadIdx.x & 63;
  if (row >= NW) return;
  const float* e = emb + (size_t)row * DIM;
  const uint* h = Hb + (size_t)row * PD_U;
  float x[6], ev[6];
  float sum = 0.f, sq = 0.f;
  #pragma unroll
  for (int j = 0; j < 3; ++j){
    int i = lane + j * 64;
    float e0 = 0.f, e1 = 0.f, h0 = 0.f, h1 = 0.f;
    if (i < 150){
      uint u = h[i];
      h0 = b2f_lo(u); h1 = b2f_hi(u);
      e0 = e[2 * i]; e1 = e[2 * i + 1];
    }
    float v0 = 0.3f * e0 + 0.7f * h0;
    float v1 = 0.3f * e1 + 0.7f * h1;
    if (i >= 150){ v0 = 0.f; v1 = 0.f; }
    x[2*j] = v0; x[2*j+1] = v1; ev[2*j] = e0; ev[2*j+1] = e1;
    sum += v0 + v1; sq += v0 * v0 + v1 * v1;
  }
  #pragma unroll
  for (int o = 32; o > 0; o >>= 1){ sum += __shfl_down(sum, o); sq += __shfl_down(sq, o); }
  sum = __shfl(sum, 0); sq = __shfl(sq, 0);
  const float inv = 1.f / (float)DIM;
  float mu = sum * inv;
  float var = sq * inv - mu * mu;
  float rs = rsqrtf(var + 1e-5f);
  uint* o = S + (size_t)row * PD_U;
  #pragma unroll
  for (int j = 0; j < 3; ++j){
    int i = lane + j * 64;
    if (i >= PD_U) continue;
    uint w = 0;
    if (i < 150){
      float r0 = (x[2*j]   - mu) * rs * g[2*i]   + bb[2*i]   + ev[2*j];
      float r1 = (x[2*j+1] - mu) * rs * g[2*i+1] + bb[2*i+1] + ev[2*j+1];
      w = packb(r0, r1);
    }
    o[i] = w;
  }
}

// ---------------- classifier: [ND,150]bf16 @ [2,150]^T + b -> fp32 out ----------------
__global__ void k_clf(const uint* __restrict__ h2, const float* __restrict__ w,
                      const float* __restrict__ bias, float* __restrict__ out){
  int m = blockIdx.x * blockDim.x + threadIdx.x;
  if (m >= ND) return;
  const uint* hr = h2 + (size_t)m * 80;
  float s0 = bias[0], s1 = bias[1];
  #pragma unroll 5
  for (int i = 0; i < 75; ++i){
    uint u = hr[i];
    float h0 = b2f_lo(u), h1 = b2f_hi(u);
    int k = 2 * i;
    s0 = fmaf(h0, w[k], fmaf(h1, w[k + 1], s0));
    s1 = fmaf(h0, w[DIM2 + k], fmaf(h1, w[DIM2 + k + 1], s1));
  }
  out[m * 2] = s0;
  out[m * 2 + 1] = s1;
}

extern "C" void kernel_launch(void* const* d_in, const int* in_sizes, int n_in,
                              void* d_out, int out_size, void* d_ws, size_t ws_size,
                              hipStream_t stream){
  const int*   a_rows = (const int*)  d_in[0];
  const int*   a_cols = (const int*)  d_in[1];
  const float* a_vals = (const float*)d_in[2];
  const int*   x_rows = (const int*)  d_in[3];
  const int*   x_cols = (const int*)  d_in[4];
  const float* x_vals = (const float*)d_in[5];
  const float* emb    = (const float*)d_in[6];
  const float* w1     = (const float*)d_in[7];
  const float* w2     = (const float*)d_in[8];
  const float* w3     = (const float*)d_in[9];
  const float* ln_g   = (const float*)d_in[10];
  const float* ln_b   = (const float*)d_in[11];
  const float* m_w1   = (const float*)d_in[12];
  const float* m_b1   = (const float*)d_in[13];
  const float* bn1_g  = (const float*)d_in[14];
  const float* bn1_b  = (const float*)d_in[15];
  const float* m_w2   = (const float*)d_in[16];
  const float* m_b2   = (const float*)d_in[17];
  const float* bn2_g  = (const float*)d_in[18];
  const float* bn2_b  = (const float*)d_in[19];
  const float* clf_w  = (const float*)d_in[20];
  const float* clf_b  = (const float*)d_in[21];
  float* out = (float*)d_out;

  char* ws = (char*)d_ws;
  size_t off = 0;
  auto take = [&](size_t nbytes)->void*{
    void* p = ws + off;
    off += (nbytes + 255) & ~(size_t)255;
    return p;
  };
  int*    a_rp   = (int*)   take((NW + 1) * 4);
  int*    a_cs   = (int*)   take((size_t)NNZA * 4);
  float*  a_vs   = (float*) take((size_t)NNZA * 4);
  int*    x_rp   = (int*)   take((ND + 1) * 4);
  int*    x_cs   = (int*)   take((size_t)NNZX * 4);
  float*  x_vs   = (float*) take((size_t)NNZX * 4);
  int*    cursor = (int*)   take((size_t)NW * 4);
  int*    bsums  = (int*)   take(64 * 4);
  ushort* embb   = (ushort*)take((size_t)NW * PD * 2);
  ushort* Tb     = (ushort*)take((size_t)NW * PD * 2);
  ushort* Hb     = (ushort*)take((size_t)NW * PD * 2);
  ushort* w1b    = (ushort*)take((size_t)PD * PD * 2);
  ushort* w2b    = (ushort*)take((size_t)PD * PD * 2);
  ushort* w3b    = (ushort*)take((size_t)PD * PD * 2);
  ushort* mw1b   = (ushort*)take((size_t)PD * PD * 2);
  ushort* mw2b   = (ushort*)take((size_t)PD * PD * 2);
  // doc-stage buffers alias Hb (word H3 is dead once res_ln has produced S in Tb)
  ushort* docHb = Hb;
  ushort* h1b   = Hb + (size_t)ND * PD;
  ushort* h2b   = Hb + (size_t)2 * ND * PD;  // stride 160

  // ---- CSR build for A ----
  int nbA = cdiv(NW, 1024);
  hipMemsetAsync(cursor, 0, NW * 4, stream);
  k_hist<<<cdiv(NNZA, 256), 256, 0, stream>>>(a_rows, NNZA, cursor);
  k_bsum<<<nbA, 1024, 0, stream>>>(cursor, NW, bsums);
  k_scan_small<<<1, 64, 0, stream>>>(bsums, nbA, a_rp, NW);
  k_scan_apply<<<nbA, 1024, 0, stream>>>(cursor, NW, bsums, a_rp, cursor);
  k_scatter<<<cdiv(NNZA, 256), 256, 0, stream>>>(a_rows, a_cols, a_vals, NNZA, cursor, a_cs, a_vs);
  // ---- CSR build for X ----
  int nbX = cdiv(ND, 1024);
  hipMemsetAsync(cursor, 0, ND * 4, stream);
  k_hist<<<cdiv(NNZX, 256), 256, 0, stream>>>(x_rows, NNZX, cursor);
  k_bsum<<<nbX, 1024, 0, stream>>>(cursor, ND, bsums);
  k_scan_small<<<1, 64, 0, stream>>>(bsums, nbX, x_rp, ND);
  k_scan_apply<<<nbX, 1024, 0, stream>>>(cursor, ND, bsums, x_rp, cursor);
  k_scatter<<<cdiv(NNZX, 256), 256, 0, stream>>>(x_rows, x_cols, x_vals, NNZX, cursor, x_cs, x_vs);

  // ---- fp32 -> bf16 padded conversions ----
  k_f2b_pad8<<<cdiv(NW * 40, 256), 256, 0, stream>>>(emb, embb, NW, DIM, NW, PD);
  dim3 gw(cdiv(PD * 40, 256), 5);
  k_f2b_w5<<<gw, 256, 0, stream>>>(w1, w2, w3, m_w1, m_w2, w1b, w2b, w3b, mw1b, mw2b);

  // ---- word GCN ----
  dim3 gg(2, cdiv(NW, 128));
  k_spmm_b<<<cdiv(NW, 4), 256, 0, stream>>>(a_rp, a_cs, a_vs, (const uint*)embb, (uint*)Tb, NW);
  k_mgemm<<<gg, 256, 0, stream>>>(Tb, w1b, nullptr, nullptr, nullptr, Hb, NW, DIM, PD, 1);
  k_spmm_b<<<cdiv(NW, 4), 256, 0, stream>>>(a_rp, a_cs, a_vs, (const uint*)Hb, (uint*)Tb, NW);
  k_mgemm<<<gg, 256, 0, stream>>>(Tb, w2b, nullptr, nullptr, nullptr, Hb, NW, DIM, PD, 1);
  k_spmm_b<<<cdiv(NW, 4), 256, 0, stream>>>(a_rp, a_cs, a_vs, (const uint*)Hb, (uint*)Tb, NW);
  k_mgemm<<<gg, 256, 0, stream>>>(Tb, w3b, nullptr, nullptr, nullptr, Hb, NW, DIM, PD, 1);
  // ---- residual + LN (S = LN + emb fused into Tb) ----
  k_res_ln<<<cdiv(NW, 4), 256, 0, stream>>>(emb, (const uint*)Hb, ln_g, ln_b, (uint*)Tb);
  // ---- doc aggregation (single SpMM over summed matrix) ----
  k_spmm_b<<<cdiv(ND, 4), 256, 0, stream>>>(x_rp, x_cs, x_vs, (const uint*)Tb, (uint*)docHb, ND);
  // ---- MLP head ----
  dim3 g1(2, cdiv(ND, 128));
  k_mgemm<<<g1, 256, 0, stream>>>(docHb, mw1b, m_b1, bn1_g, bn1_b, h1b, ND, DIM, PD, 1);
  dim3 g2(1, cdiv(ND, 128));
  k_mgemm<<<g2, 256, 0, stream>>>(h1b, mw2b, m_b2, bn2_g, bn2_b, h2b, ND, DIM2, 160, 1);
  k_clf<<<cdiv(ND, 256), 256, 0, stream>>>((const uint*)h2b, clf_w, clf_b, out);
}

// Round 11
// 506.990 us; speedup vs baseline: 1.8162x; 1.0642x over previous
//
#include <hip/hip_runtime.h>

#define NW 30000
#define ND 8192
#define DIM 300
#define DIM2 150
#define NNZA 600000
#define NNZX 524288
#define PD 320            // padded feature stride (bf16 elems)
#define PD_U 160          // padded stride in uint (2 bf16 each)
#define NBA 30            // cdiv(NW,1024)
#define NBX 8             // cdiv(ND,1024)
#define BN_SCALE 0.99999500003749971f

typedef unsigned int uint;
typedef unsigned short ushort;
typedef __attribute__((ext_vector_type(8))) short bf16x8;
typedef __attribute__((ext_vector_type(4))) float f32x4;
typedef __attribute__((ext_vector_type(4))) uint uint4v;

static inline int cdiv(int a, int b){ return (a + b - 1) / b; }

__device__ __forceinline__ float b2f_lo(uint u){ return __builtin_bit_cast(float, u << 16); }
__device__ __forceinline__ float b2f_hi(uint u){ return __builtin_bit_cast(float, u & 0xffff0000u); }
__device__ __forceinline__ ushort f2b(float f){
  uint u = __builtin_bit_cast(uint, f);
  u += 0x7fffu + ((u >> 16) & 1u);
  return (ushort)(u >> 16);
}
__device__ __forceinline__ uint packb(float x, float y){
  return (uint)f2b(x) | ((uint)f2b(y) << 16);
}

// ---------------- CSR build (A and X fused via blockIdx.y) ----------------
__global__ void k_hist2(const int* __restrict__ ra, const int* __restrict__ rx,
                        int* __restrict__ cntA, int* __restrict__ cntX){
  int i = blockIdx.x * blockDim.x + threadIdx.x;
  if (blockIdx.y == 0){
    if (i < NNZA) atomicAdd(&cntA[ra[i]], 1);
  } else {
    if (i < NNZX) atomicAdd(&cntX[rx[i]], 1);
  }
}

__global__ __launch_bounds__(1024) void k_bsum2(const int* __restrict__ cntA, const int* __restrict__ cntX,
                                                int* __restrict__ bsA, int* __restrict__ bsX){
  __shared__ int sd[1024];
  const int* cnt; int n; int* bs;
  if (blockIdx.y == 0){ cnt = cntA; n = NW; bs = bsA; }
  else                { cnt = cntX; n = ND; bs = bsX; }
  int t = threadIdx.x;
  int i = blockIdx.x * 1024 + t;
  sd[t] = (i < n) ? cnt[i] : 0;
  __syncthreads();
  #pragma unroll
  for (int o = 512; o > 0; o >>= 1){
    if (t < o) sd[t] += sd[t + o];
    __syncthreads();
  }
  if (t == 0) bs[blockIdx.x] = sd[0];
}

// one block, 128 threads: wave 0 scans A block-sums, wave 1 scans X block-sums
__global__ __launch_bounds__(128) void k_scan_small2(int* __restrict__ bsA, int* __restrict__ bsX,
                                                     int* __restrict__ a_rp, int* __restrict__ x_rp){
  int w = threadIdx.x >> 6, lane = threadIdx.x & 63;
  int* bs = w ? bsX : bsA;
  int nb  = w ? NBX : NBA;
  int* rp = w ? x_rp : a_rp;
  int n   = w ? ND : NW;
  int orig = (lane < nb) ? bs[lane] : 0;
  int v = orig;
  #pragma unroll
  for (int o = 1; o < 64; o <<= 1){
    int x = __shfl_up(v, o);
    if (lane >= o) v += x;
  }
  if (lane < nb) bs[lane] = v - orig;
  if (lane == nb - 1) rp[n] = v;
}

// per-block scan + offset; writes BOTH rp and the scatter cursor
__global__ __launch_bounds__(1024) void k_scan_apply2(const int* __restrict__ cntA, const int* __restrict__ cntX,
        const int* __restrict__ bsA, const int* __restrict__ bsX,
        int* __restrict__ a_rp, int* __restrict__ x_rp,
        int* __restrict__ curA, int* __restrict__ curX){
  __shared__ int sd[1024];
  const int* cnt; const int* bs; int n; int* rp; int* cur;
  if (blockIdx.y == 0){ cnt = cntA; bs = bsA; n = NW; rp = a_rp; cur = curA; }
  else                { cnt = cntX; bs = bsX; n = ND; rp = x_rp; cur = curX; }
  int t = threadIdx.x;
  int i = blockIdx.x * 1024 + t;
  int v = (i < n) ? cnt[i] : 0;
  sd[t] = v;
  __syncthreads();
  for (int o = 1; o < 1024; o <<= 1){
    int x = (t >= o) ? sd[t - o] : 0;
    __syncthreads();
    sd[t] += x;
    __syncthreads();
  }
  if (i < n){
    int start = bs[blockIdx.x] + sd[t] - v;
    rp[i] = start;
    cur[i] = start;
  }
}

// ---------------- fused prep: scatter A, scatter X, emb convert, 5 weight converts ---------
__global__ void k_prep(const int* __restrict__ a_rows, const int* __restrict__ a_cols, const float* __restrict__ a_vals,
                       const int* __restrict__ x_rows, const int* __restrict__ x_cols, const float* __restrict__ x_vals,
                       int* __restrict__ curA, int* __restrict__ curX,
                       int* __restrict__ a_cs, float* __restrict__ a_vs,
                       int* __restrict__ x_cs, float* __restrict__ x_vs,
                       const float* __restrict__ emb, ushort* __restrict__ embb,
                       const float* __restrict__ w1, const float* __restrict__ w2, const float* __restrict__ w3,
                       const float* __restrict__ mw1, const float* __restrict__ mw2,
                       ushort* __restrict__ w1b, ushort* __restrict__ w2b, ushort* __restrict__ w3b,
                       ushort* __restrict__ mw1b, ushort* __restrict__ mw2b){
  int y = blockIdx.y;
  int gi = blockIdx.x * blockDim.x + threadIdx.x;
  if (y == 0){
    if (gi < NNZA){
      int r = a_rows[gi];
      int p = atomicAdd(&curA[r], 1);
      a_cs[p] = a_cols[gi];
      a_vs[p] = a_vals[gi];
    }
  } else if (y == 1){
    if (gi < NNZX){
      int r = x_rows[gi];
      int p = atomicAdd(&curX[r], 1);
      x_cs[p] = x_cols[gi];
      x_vs[p] = x_vals[gi];
    }
  } else if (y == 2){
    if (gi < NW * 40){
      int r = gi / 40;
      int c = (gi - r * 40) << 3;
      float x[8];
      #pragma unroll
      for (int j = 0; j < 8; ++j)
        x[j] = (c + j < DIM) ? emb[(size_t)r * DIM + c + j] : 0.f;
      uint4v o;
      o.x = packb(x[0], x[1]); o.y = packb(x[2], x[3]);
      o.z = packb(x[4], x[5]); o.w = packb(x[6], x[7]);
      *(uint4v*)(embb + (size_t)r * PD + c) = o;
    }
  } else {
    if (gi < PD * 40){
      int r = gi / 40;
      int c = (gi - r * 40) << 3;
      const float* src; ushort* dst; int srows;
      if      (y == 3){ src = w1;  dst = w1b;  srows = DIM;  }
      else if (y == 4){ src = w2;  dst = w2b;  srows = DIM;  }
      else if (y == 5){ src = w3;  dst = w3b;  srows = DIM;  }
      else if (y == 6){ src = mw1; dst = mw1b; srows = DIM;  }
      else            { src = mw2; dst = mw2b; srows = DIM2; }
      float x[8];
      #pragma unroll
      for (int j = 0; j < 8; ++j)
        x[j] = (r < srows && c + j < DIM) ? src[(size_t)r * DIM + c + j] : 0.f;
      uint4v o;
      o.x = packb(x[0], x[1]); o.y = packb(x[2], x[3]);
      o.z = packb(x[4], x[5]); o.w = packb(x[6], x[7]);
      *(uint4v*)(dst + (size_t)r * PD + c) = o;
    }
  }
}

// ---------------- SpMM over bf16 table: one wave per row, unroll-4 (proven) ----------------
__global__ __launch_bounds__(256) void k_spmm_b(const int* __restrict__ rp, const int* __restrict__ cs,
        const float* __restrict__ vs, const uint* __restrict__ Hb, uint* __restrict__ Ob, int nrows){
  int wid = (blockIdx.x * blockDim.x + threadIdx.x) >> 6;
  int lane = threadIdx.x & 63;
  if (wid >= nrows) return;
  int s = rp[wid], e = rp[wid + 1];
  const bool half = lane < 32;
  float acc[4][6] = {};
  int k = s;
  for (; k + 4 <= e; k += 4){
    #pragma unroll
    for (int j = 0; j < 4; ++j){
      int c = cs[k + j];
      float v = vs[k + j];
      const uint* p = Hb + (size_t)c * PD_U;
      uint u0 = p[lane], u1 = p[lane + 64];
      uint u2 = half ? p[lane + 128] : 0;
      acc[j][0] = fmaf(v, b2f_lo(u0), acc[j][0]);
      acc[j][1] = fmaf(v, b2f_hi(u0), acc[j][1]);
      acc[j][2] = fmaf(v, b2f_lo(u1), acc[j][2]);
      acc[j][3] = fmaf(v, b2f_hi(u1), acc[j][3]);
      acc[j][4] = fmaf(v, b2f_lo(u2), acc[j][4]);
      acc[j][5] = fmaf(v, b2f_hi(u2), acc[j][5]);
    }
  }
  for (; k < e; ++k){
    int c = cs[k];
    float v = vs[k];
    const uint* p = Hb + (size_t)c * PD_U;
    uint u0 = p[lane], u1 = p[lane + 64];
    uint u2 = half ? p[lane + 128] : 0;
    acc[0][0] = fmaf(v, b2f_lo(u0), acc[0][0]);
    acc[0][1] = fmaf(v, b2f_hi(u0), acc[0][1]);
    acc[0][2] = fmaf(v, b2f_lo(u1), acc[0][2]);
    acc[0][3] = fmaf(v, b2f_hi(u1), acc[0][3]);
    acc[0][4] = fmaf(v, b2f_lo(u2), acc[0][4]);
    acc[0][5] = fmaf(v, b2f_hi(u2), acc[0][5]);
  }
  #pragma unroll
  for (int d = 0; d < 6; ++d)
    acc[0][d] += (acc[1][d] + acc[2][d]) + acc[3][d];
  uint* o = Ob + (size_t)wid * PD_U;
  o[lane] = packb(acc[0][0], acc[0][1]);
  o[lane + 64] = packb(acc[0][2], acc[0][3]);
  if (half) o[lane + 128] = packb(acc[0][4], acc[0][5]);
}

// ---------------- MFMA GEMM: C[M,Nvalid] = act(A[M,320]bf16 @ B[n][k]bf16^T) (proven) ------
// BM=128, BN=160, BK=64, 4 waves (2x2), wave tile 64x80 (4x5 16x16 frags).
__global__ __launch_bounds__(256) void k_mgemm(const ushort* __restrict__ A, const ushort* __restrict__ B,
        const float* __restrict__ bias, const float* __restrict__ bng, const float* __restrict__ bnb,
        ushort* __restrict__ C, int M, int Nvalid, int ldc, int relu){
  __shared__ ushort As[128][72];
  __shared__ ushort Bs[160][72];
  const int t = threadIdx.x;
  const int wid = t >> 6, lane = t & 63;
  const int bm = blockIdx.y << 7;
  const int bn = blockIdx.x * 160;
  const int wm = (wid >> 1) << 6;   // 0 / 64
  const int wn = (wid & 1) * 80;    // 0 / 80
  const int r16 = lane & 15;
  const int h8 = (lane >> 4) << 3;  // k-offset within 32
  f32x4 acc[4][5] = {};
  for (int k0 = 0; k0 < PD; k0 += 64){
    #pragma unroll
    for (int i = 0; i < 4; ++i){
      int q = t + (i << 8);
      int r = q >> 3, c = (q & 7) << 3;
      int gm = bm + r; if (gm >= M) gm = M - 1;
      *(bf16x8*)(&As[r][c]) = *(const bf16x8*)(A + (size_t)gm * PD + k0 + c);
    }
    #pragma unroll
    for (int i = 0; i < 5; ++i){
      int q = t + (i << 8);
      int r = q >> 3, c = (q & 7) << 3;
      *(bf16x8*)(&Bs[r][c]) = *(const bf16x8*)(B + (size_t)(bn + r) * PD + k0 + c);
    }
    __syncthreads();
    #pragma unroll
    for (int kk = 0; kk < 2; ++kk){
      bf16x8 af[4], bfr[5];
      #pragma unroll
      for (int m = 0; m < 4; ++m)
        af[m] = *(const bf16x8*)(&As[wm + m * 16 + r16][kk * 32 + h8]);
      #pragma unroll
      for (int n = 0; n < 5; ++n)
        bfr[n] = *(const bf16x8*)(&Bs[wn + n * 16 + r16][kk * 32 + h8]);
      #pragma unroll
      for (int m = 0; m < 4; ++m)
        #pragma unroll
        for (int n = 0; n < 5; ++n)
          acc[m][n] = __builtin_amdgcn_mfma_f32_16x16x32_bf16(af[m], bfr[n], acc[m][n], 0, 0, 0);
    }
    __syncthreads();
  }
  const int cr = (lane >> 4) << 2;
  #pragma unroll
  for (int m = 0; m < 4; ++m){
    #pragma unroll
    for (int n = 0; n < 5; ++n){
      int col = bn + wn + n * 16 + r16;
      #pragma unroll
      for (int j = 0; j < 4; ++j){
        int row = bm + wm + m * 16 + cr + j;
        if (row >= M) continue;
        float v = acc[m][n][j];
        if (col < Nvalid){
          if (bias) v += bias[col];
          if (bng)  v = v * (bng[col] * BN_SCALE) + bnb[col];
          if (relu) v = fmaxf(v, 0.f);
        } else v = 0.f;
        C[(size_t)row * ldc + col] = f2b(v);
      }
    }
  }
}

// ---------------- residual + LayerNorm; S = LN(0.3*emb + 0.7*H) + emb (bf16 emb input) ------
__global__ __launch_bounds__(256) void k_res_ln(const uint* __restrict__ E, const uint* __restrict__ Hb,
        const float* __restrict__ g, const float* __restrict__ bb, uint* __restrict__ S){
  int row = blockIdx.x * 4 + (threadIdx.x >> 6);
  int lane = threadIdx.x & 63;
  if (row >= NW) return;
  const uint* e = E + (size_t)row * PD_U;
  const uint* h = Hb + (size_t)row * PD_U;
  float x[6], ev[6];
  float sum = 0.f, sq = 0.f;
  #pragma unroll
  for (int j = 0; j < 3; ++j){
    int i = lane + j * 64;
    float e0 = 0.f, e1 = 0.f, h0 = 0.f, h1 = 0.f;
    if (i < 150){
      uint u = h[i];
      uint ue = e[i];
      h0 = b2f_lo(u);  h1 = b2f_hi(u);
      e0 = b2f_lo(ue); e1 = b2f_hi(ue);
    }
    float v0 = 0.3f * e0 + 0.7f * h0;
    float v1 = 0.3f * e1 + 0.7f * h1;
    if (i >= 150){ v0 = 0.f; v1 = 0.f; }
    x[2*j] = v0; x[2*j+1] = v1; ev[2*j] = e0; ev[2*j+1] = e1;
    sum += v0 + v1; sq += v0 * v0 + v1 * v1;
  }
  #pragma unroll
  for (int o = 32; o > 0; o >>= 1){ sum += __shfl_down(sum, o); sq += __shfl_down(sq, o); }
  sum = __shfl(sum, 0); sq = __shfl(sq, 0);
  const float inv = 1.f / (float)DIM;
  float mu = sum * inv;
  float var = sq * inv - mu * mu;
  float rs = rsqrtf(var + 1e-5f);
  uint* o = S + (size_t)row * PD_U;
  #pragma unroll
  for (int j = 0; j < 3; ++j){
    int i = lane + j * 64;
    if (i >= PD_U) continue;
    uint w = 0;
    if (i < 150){
      float r0 = (x[2*j]   - mu) * rs * g[2*i]   + bb[2*i]   + ev[2*j];
      float r1 = (x[2*j+1] - mu) * rs * g[2*i+1] + bb[2*i+1] + ev[2*j+1];
      w = packb(r0, r1);
    }
    o[i] = w;
  }
}

// ---------------- classifier: wave per row; 64 lanes cover 75 uints (11 lanes take 2) -------
__global__ __launch_bounds__(256) void k_clf(const uint* __restrict__ h2, const float* __restrict__ w,
                      const float* __restrict__ bias, float* __restrict__ out){
  int row = blockIdx.x * 4 + (threadIdx.x >> 6);
  int lane = threadIdx.x & 63;
  if (row >= ND) return;
  float s0, s1;
  {
    uint u = h2[(size_t)row * 80 + lane];       // uints 0..63 (cols 0..127)
    float h0 = b2f_lo(u), h1 = b2f_hi(u);
    int k = 2 * lane;
    s0 = h0 * w[k] + h1 * w[k + 1];
    s1 = h0 * w[DIM2 + k] + h1 * w[DIM2 + k + 1];
  }
  if (lane < 11){
    uint u = h2[(size_t)row * 80 + 64 + lane];  // uints 64..74 (cols 128..149)
    float h0 = b2f_lo(u), h1 = b2f_hi(u);
    int k = 2 * (64 + lane);
    s0 += h0 * w[k] + h1 * w[k + 1];
    s1 += h0 * w[DIM2 + k] + h1 * w[DIM2 + k + 1];
  }
  #pragma unroll
  for (int o = 32; o > 0; o >>= 1){
    s0 += __shfl_down(s0, o);
    s1 += __shfl_down(s1, o);
  }
  if (lane == 0){
    out[row * 2]     = s0 + bias[0];
    out[row * 2 + 1] = s1 + bias[1];
  }
}

extern "C" void kernel_launch(void* const* d_in, const int* in_sizes, int n_in,
                              void* d_out, int out_size, void* d_ws, size_t ws_size,
                              hipStream_t stream){
  const int*   a_rows = (const int*)  d_in[0];
  const int*   a_cols = (const int*)  d_in[1];
  const float* a_vals = (const float*)d_in[2];
  const int*   x_rows = (const int*)  d_in[3];
  const int*   x_cols = (const int*)  d_in[4];
  const float* x_vals = (const float*)d_in[5];
  const float* emb    = (const float*)d_in[6];
  const float* w1     = (const float*)d_in[7];
  const float* w2     = (const float*)d_in[8];
  const float* w3     = (const float*)d_in[9];
  const float* ln_g   = (const float*)d_in[10];
  const float* ln_b   = (const float*)d_in[11];
  const float* m_w1   = (const float*)d_in[12];
  const float* m_b1   = (const float*)d_in[13];
  const float* bn1_g  = (const float*)d_in[14];
  const float* bn1_b  = (const float*)d_in[15];
  const float* m_w2   = (const float*)d_in[16];
  const float* m_b2   = (const float*)d_in[17];
  const float* bn2_g  = (const float*)d_in[18];
  const float* bn2_b  = (const float*)d_in[19];
  const float* clf_w  = (const float*)d_in[20];
  const float* clf_b  = (const float*)d_in[21];
  float* out = (float*)d_out;

  char* ws = (char*)d_ws;
  size_t off = 0;
  auto take = [&](size_t nbytes)->void*{
    void* p = ws + off;
    off += (nbytes + 255) & ~(size_t)255;
    return p;
  };
  int*    a_rp   = (int*)   take((NW + 1) * 4);
  int*    a_cs   = (int*)   take((size_t)NNZA * 4);
  float*  a_vs   = (float*) take((size_t)NNZA * 4);
  int*    x_rp   = (int*)   take((ND + 1) * 4);
  int*    x_cs   = (int*)   take((size_t)NNZX * 4);
  float*  x_vs   = (float*) take((size_t)NNZX * 4);
  int*    cursors= (int*)   take((size_t)(NW + ND) * 4);
  int*    bsA    = (int*)   take(64 * 4);
  int*    bsX    = (int*)   take(64 * 4);
  ushort* embb   = (ushort*)take((size_t)NW * PD * 2);
  ushort* Tb     = (ushort*)take((size_t)NW * PD * 2);
  ushort* Hb     = (ushort*)take((size_t)NW * PD * 2);
  ushort* w1b    = (ushort*)take((size_t)PD * PD * 2);
  ushort* w2b    = (ushort*)take((size_t)PD * PD * 2);
  ushort* w3b    = (ushort*)take((size_t)PD * PD * 2);
  ushort* mw1b   = (ushort*)take((size_t)PD * PD * 2);
  ushort* mw2b   = (ushort*)take((size_t)PD * PD * 2);
  int* curA = cursors;
  int* curX = cursors + NW;
  // doc-stage buffers alias Hb (word H3 is dead once res_ln has produced S in Tb)
  ushort* docHb = Hb;
  ushort* h1b   = Hb + (size_t)ND * PD;
  ushort* h2b   = Hb + (size_t)2 * ND * PD;  // stride 160

  // ---- fused CSR build (A and X) ----
  hipMemsetAsync(cursors, 0, (size_t)(NW + ND) * 4, stream);
  dim3 gh(cdiv(NNZA, 256), 2);
  k_hist2<<<gh, 256, 0, stream>>>(a_rows, x_rows, curA, curX);
  dim3 gb(NBA, 2);
  k_bsum2<<<gb, 1024, 0, stream>>>(curA, curX, bsA, bsX);
  k_scan_small2<<<1, 128, 0, stream>>>(bsA, bsX, a_rp, x_rp);
  k_scan_apply2<<<gb, 1024, 0, stream>>>(curA, curX, bsA, bsX, a_rp, x_rp, curA, curX);
  // ---- fused prep: scatters + all bf16 converts ----
  dim3 gp(cdiv(NW * 40, 256), 8);
  k_prep<<<gp, 256, 0, stream>>>(a_rows, a_cols, a_vals, x_rows, x_cols, x_vals,
                                 curA, curX, a_cs, a_vs, x_cs, x_vs,
                                 emb, embb, w1, w2, w3, m_w1, m_w2,
                                 w1b, w2b, w3b, mw1b, mw2b);

  // ---- word GCN ----
  dim3 gg(2, cdiv(NW, 128));
  k_spmm_b<<<cdiv(NW, 4), 256, 0, stream>>>(a_rp, a_cs, a_vs, (const uint*)embb, (uint*)Tb, NW);
  k_mgemm<<<gg, 256, 0, stream>>>(Tb, w1b, nullptr, nullptr, nullptr, Hb, NW, DIM, PD, 1);
  k_spmm_b<<<cdiv(NW, 4), 256, 0, stream>>>(a_rp, a_cs, a_vs, (const uint*)Hb, (uint*)Tb, NW);
  k_mgemm<<<gg, 256, 0, stream>>>(Tb, w2b, nullptr, nullptr, nullptr, Hb, NW, DIM, PD, 1);
  k_spmm_b<<<cdiv(NW, 4), 256, 0, stream>>>(a_rp, a_cs, a_vs, (const uint*)Hb, (uint*)Tb, NW);
  k_mgemm<<<gg, 256, 0, stream>>>(Tb, w3b, nullptr, nullptr, nullptr, Hb, NW, DIM, PD, 1);
  // ---- residual + LN (S = LN + emb fused into Tb; emb read as bf16) ----
  k_res_ln<<<cdiv(NW, 4), 256, 0, stream>>>((const uint*)embb, (const uint*)Hb, ln_g, ln_b, (uint*)Tb);
  // ---- doc aggregation (single SpMM over summed matrix) ----
  k_spmm_b<<<cdiv(ND, 4), 256, 0, stream>>>(x_rp, x_cs, x_vs, (const uint*)Tb, (uint*)docHb, ND);
  // ---- MLP head ----
  dim3 g1(2, cdiv(ND, 128));
  k_mgemm<<<g1, 256, 0, stream>>>(docHb, mw1b, m_b1, bn1_g, bn1_b, h1b, ND, DIM, PD, 1);
  dim3 g2(1, cdiv(ND, 128));
  k_mgemm<<<g2, 256, 0, stream>>>(h1b, mw2b, m_b2, bn2_g, bn2_b, h2b, ND, DIM2, 160, 1);
  k_clf<<<cdiv(ND, 4), 256, 0, stream>>>((const uint*)h2b, clf_w, clf_b, out);
}

// Round 13
// 505.748 us; speedup vs baseline: 1.8206x; 1.0025x over previous
//
#include <hip/hip_runtime.h>

#define NW 30000
#define ND 8192
#define DIM 300
#define DIM2 150
#define NNZA 600000
#define NNZX 524288
#define PD 320            // padded feature stride (bf16 elems)
#define PD_U 160          // padded stride in uint (2 bf16 each)
#define NBA 30            // cdiv(NW,1024)
#define NBX 8             // cdiv(ND,1024)
#define BN_SCALE 0.99999500003749971f

typedef unsigned int uint;
typedef unsigned short ushort;
typedef __attribute__((ext_vector_type(8))) short bf16x8;
typedef __attribute__((ext_vector_type(4))) float f32x4;
typedef __attribute__((ext_vector_type(4))) uint uint4v;

static inline int cdiv(int a, int b){ return (a + b - 1) / b; }

__device__ __forceinline__ float b2f_lo(uint u){ return __builtin_bit_cast(float, u << 16); }
__device__ __forceinline__ float b2f_hi(uint u){ return __builtin_bit_cast(float, u & 0xffff0000u); }
__device__ __forceinline__ ushort f2b(float f){
  uint u = __builtin_bit_cast(uint, f);
  u += 0x7fffu + ((u >> 16) & 1u);
  return (ushort)(u >> 16);
}
__device__ __forceinline__ uint packb(float x, float y){
  return (uint)f2b(x) | ((uint)f2b(y) << 16);
}

// ---------------- CSR build (A and X fused via blockIdx.y) ----------------
__global__ void k_hist2(const int* __restrict__ ra, const int* __restrict__ rx,
                        int* __restrict__ cntA, int* __restrict__ cntX){
  int i = blockIdx.x * blockDim.x + threadIdx.x;
  if (blockIdx.y == 0){
    if (i < NNZA) atomicAdd(&cntA[ra[i]], 1);
  } else {
    if (i < NNZX) atomicAdd(&cntX[rx[i]], 1);
  }
}

__global__ __launch_bounds__(1024) void k_bsum2(const int* __restrict__ cntA, const int* __restrict__ cntX,
                                                int* __restrict__ bsA, int* __restrict__ bsX){
  __shared__ int sd[1024];
  const int* cnt; int n; int* bs;
  if (blockIdx.y == 0){ cnt = cntA; n = NW; bs = bsA; }
  else                { cnt = cntX; n = ND; bs = bsX; }
  int t = threadIdx.x;
  int i = blockIdx.x * 1024 + t;
  sd[t] = (i < n) ? cnt[i] : 0;
  __syncthreads();
  #pragma unroll
  for (int o = 512; o > 0; o >>= 1){
    if (t < o) sd[t] += sd[t + o];
    __syncthreads();
  }
  if (t == 0) bs[blockIdx.x] = sd[0];
}

// one block, 128 threads: wave 0 scans A block-sums, wave 1 scans X block-sums
__global__ __launch_bounds__(128) void k_scan_small2(int* __restrict__ bsA, int* __restrict__ bsX,
                                                     int* __restrict__ a_rp, int* __restrict__ x_rp){
  int w = threadIdx.x >> 6, lane = threadIdx.x & 63;
  int* bs = w ? bsX : bsA;
  int nb  = w ? NBX : NBA;
  int* rp = w ? x_rp : a_rp;
  int n   = w ? ND : NW;
  int orig = (lane < nb) ? bs[lane] : 0;
  int v = orig;
  #pragma unroll
  for (int o = 1; o < 64; o <<= 1){
    int x = __shfl_up(v, o);
    if (lane >= o) v += x;
  }
  if (lane < nb) bs[lane] = v - orig;
  if (lane == nb - 1) rp[n] = v;
}

// per-block scan + offset; writes BOTH rp and the scatter cursor
__global__ __launch_bounds__(1024) void k_scan_apply2(const int* __restrict__ cntA, const int* __restrict__ cntX,
        const int* __restrict__ bsA, const int* __restrict__ bsX,
        int* __restrict__ a_rp, int* __restrict__ x_rp,
        int* __restrict__ curA, int* __restrict__ curX){
  __shared__ int sd[1024];
  const int* cnt; const int* bs; int n; int* rp; int* cur;
  if (blockIdx.y == 0){ cnt = cntA; bs = bsA; n = NW; rp = a_rp; cur = curA; }
  else                { cnt = cntX; bs = bsX; n = ND; rp = x_rp; cur = curX; }
  int t = threadIdx.x;
  int i = blockIdx.x * 1024 + t;
  int v = (i < n) ? cnt[i] : 0;
  sd[t] = v;
  __syncthreads();
  for (int o = 1; o < 1024; o <<= 1){
    int x = (t >= o) ? sd[t - o] : 0;
    __syncthreads();
    sd[t] += x;
    __syncthreads();
  }
  if (i < n){
    int start = bs[blockIdx.x] + sd[t] - v;
    rp[i] = start;
    cur[i] = start;
  }
}

// ---- fused prep: scatter A, scatter X (interleaved col/val, scalar stores), emb + 5 weights ----
__global__ void k_prep(const int* __restrict__ a_rows, const int* __restrict__ a_cols, const float* __restrict__ a_vals,
                       const int* __restrict__ x_rows, const int* __restrict__ x_cols, const float* __restrict__ x_vals,
                       int* __restrict__ curA, int* __restrict__ curX,
                       int* __restrict__ a_iv, int* __restrict__ x_iv,
                       const float* __restrict__ emb, ushort* __restrict__ embb,
                       const float* __restrict__ w1, const float* __restrict__ w2, const float* __restrict__ w3,
                       const float* __restrict__ mw1, const float* __restrict__ mw2,
                       ushort* __restrict__ w1b, ushort* __restrict__ w2b, ushort* __restrict__ w3b,
                       ushort* __restrict__ mw1b, ushort* __restrict__ mw2b){
  int y = blockIdx.y;
  int gi = blockIdx.x * blockDim.x + threadIdx.x;
  if (y == 0){
    if (gi < NNZA){
      int r = a_rows[gi];
      int p = atomicAdd(&curA[r], 1);
      a_iv[2 * p]     = a_cols[gi];                          // adjacent 4B stores ->
      a_iv[2 * p + 1] = __builtin_bit_cast(int, a_vals[gi]); // one dirty line per nnz
    }
  } else if (y == 1){
    if (gi < NNZX){
      int r = x_rows[gi];
      int p = atomicAdd(&curX[r], 1);
      x_iv[2 * p]     = x_cols[gi];
      x_iv[2 * p + 1] = __builtin_bit_cast(int, x_vals[gi]);
    }
  } else if (y == 2){
    if (gi < NW * 40){
      int r = gi / 40;
      int c = (gi - r * 40) << 3;
      float x[8];
      #pragma unroll
      for (int j = 0; j < 8; ++j)
        x[j] = (c + j < DIM) ? emb[(size_t)r * DIM + c + j] : 0.f;
      uint4v o;
      o.x = packb(x[0], x[1]); o.y = packb(x[2], x[3]);
      o.z = packb(x[4], x[5]); o.w = packb(x[6], x[7]);
      *(uint4v*)(embb + (size_t)r * PD + c) = o;
    }
  } else {
    if (gi < PD * 40){
      int r = gi / 40;
      int c = (gi - r * 40) << 3;
      const float* src; ushort* dst; int srows;
      if      (y == 3){ src = w1;  dst = w1b;  srows = DIM;  }
      else if (y == 4){ src = w2;  dst = w2b;  srows = DIM;  }
      else if (y == 5){ src = w3;  dst = w3b;  srows = DIM;  }
      else if (y == 6){ src = mw1; dst = mw1b; srows = DIM;  }
      else            { src = mw2; dst = mw2b; srows = DIM2; }
      float x[8];
      #pragma unroll
      for (int j = 0; j < 8; ++j)
        x[j] = (r < srows && c + j < DIM) ? src[(size_t)r * DIM + c + j] : 0.f;
      uint4v o;
      o.x = packb(x[0], x[1]); o.y = packb(x[2], x[3]);
      o.z = packb(x[4], x[5]); o.w = packb(x[6], x[7]);
      *(uint4v*)(dst + (size_t)r * PD + c) = o;
    }
  }
}

// ---------------- SpMM over bf16 table: one wave per row, unroll-4, interleaved iv ------------
__global__ __launch_bounds__(256) void k_spmm_b(const int* __restrict__ rp, const int* __restrict__ iv,
        const uint* __restrict__ Hb, uint* __restrict__ Ob, int nrows){
  int wid = (blockIdx.x * blockDim.x + threadIdx.x) >> 6;
  int lane = threadIdx.x & 63;
  if (wid >= nrows) return;
  int s = rp[wid], e = rp[wid + 1];
  const bool half = lane < 32;
  float acc[4][6] = {};
  int k = s;
  for (; k + 4 <= e; k += 4){
    #pragma unroll
    for (int j = 0; j < 4; ++j){
      int c   = iv[2 * (k + j)];
      float v = __builtin_bit_cast(float, iv[2 * (k + j) + 1]);
      const uint* p = Hb + (size_t)c * PD_U;
      uint u0 = p[lane], u1 = p[lane + 64];
      uint u2 = half ? p[lane + 128] : 0;
      acc[j][0] = fmaf(v, b2f_lo(u0), acc[j][0]);
      acc[j][1] = fmaf(v, b2f_hi(u0), acc[j][1]);
      acc[j][2] = fmaf(v, b2f_lo(u1), acc[j][2]);
      acc[j][3] = fmaf(v, b2f_hi(u1), acc[j][3]);
      acc[j][4] = fmaf(v, b2f_lo(u2), acc[j][4]);
      acc[j][5] = fmaf(v, b2f_hi(u2), acc[j][5]);
    }
  }
  for (; k < e; ++k){
    int c   = iv[2 * k];
    float v = __builtin_bit_cast(float, iv[2 * k + 1]);
    const uint* p = Hb + (size_t)c * PD_U;
    uint u0 = p[lane], u1 = p[lane + 64];
    uint u2 = half ? p[lane + 128] : 0;
    acc[0][0] = fmaf(v, b2f_lo(u0), acc[0][0]);
    acc[0][1] = fmaf(v, b2f_hi(u0), acc[0][1]);
    acc[0][2] = fmaf(v, b2f_lo(u1), acc[0][2]);
    acc[0][3] = fmaf(v, b2f_hi(u1), acc[0][3]);
    acc[0][4] = fmaf(v, b2f_lo(u2), acc[0][4]);
    acc[0][5] = fmaf(v, b2f_hi(u2), acc[0][5]);
  }
  #pragma unroll
  for (int d = 0; d < 6; ++d)
    acc[0][d] += (acc[1][d] + acc[2][d]) + acc[3][d];
  uint* o = Ob + (size_t)wid * PD_U;
  o[lane] = packb(acc[0][0], acc[0][1]);
  o[lane + 64] = packb(acc[0][2], acc[0][3]);
  if (half) o[lane + 128] = packb(acc[0][4], acc[0][5]);
}

// ---------------- MFMA GEMM: C[M,Nvalid] = act(A[M,320]bf16 @ B[n][k]bf16^T) (proven) ------
// BM=128, BN=160, BK=64, 4 waves (2x2), wave tile 64x80 (4x5 16x16 frags).
__global__ __launch_bounds__(256) void k_mgemm(const ushort* __restrict__ A, const ushort* __restrict__ B,
        const float* __restrict__ bias, const float* __restrict__ bng, const float* __restrict__ bnb,
        ushort* __restrict__ C, int M, int Nvalid, int ldc, int relu){
  __shared__ ushort As[128][72];
  __shared__ ushort Bs[160][72];
  const int t = threadIdx.x;
  const int wid = t >> 6, lane = t & 63;
  const int bm = blockIdx.y << 7;
  const int bn = blockIdx.x * 160;
  const int wm = (wid >> 1) << 6;   // 0 / 64
  const int wn = (wid & 1) * 80;    // 0 / 80
  const int r16 = lane & 15;
  const int h8 = (lane >> 4) << 3;  // k-offset within 32
  f32x4 acc[4][5] = {};
  for (int k0 = 0; k0 < PD; k0 += 64){
    #pragma unroll
    for (int i = 0; i < 4; ++i){
      int q = t + (i << 8);
      int r = q >> 3, c = (q & 7) << 3;
      int gm = bm + r; if (gm >= M) gm = M - 1;
      *(bf16x8*)(&As[r][c]) = *(const bf16x8*)(A + (size_t)gm * PD + k0 + c);
    }
    #pragma unroll
    for (int i = 0; i < 5; ++i){
      int q = t + (i << 8);
      int r = q >> 3, c = (q & 7) << 3;
      *(bf16x8*)(&Bs[r][c]) = *(const bf16x8*)(B + (size_t)(bn + r) * PD + k0 + c);
    }
    __syncthreads();
    #pragma unroll
    for (int kk = 0; kk < 2; ++kk){
      bf16x8 af[4], bfr[5];
      #pragma unroll
      for (int m = 0; m < 4; ++m)
        af[m] = *(const bf16x8*)(&As[wm + m * 16 + r16][kk * 32 + h8]);
      #pragma unroll
      for (int n = 0; n < 5; ++n)
        bfr[n] = *(const bf16x8*)(&Bs[wn + n * 16 + r16][kk * 32 + h8]);
      #pragma unroll
      for (int m = 0; m < 4; ++m)
        #pragma unroll
        for (int n = 0; n < 5; ++n)
          acc[m][n] = __builtin_amdgcn_mfma_f32_16x16x32_bf16(af[m], bfr[n], acc[m][n], 0, 0, 0);
    }
    __syncthreads();
  }
  const int cr = (lane >> 4) << 2;
  #pragma unroll
  for (int m = 0; m < 4; ++m){
    #pragma unroll
    for (int n = 0; n < 5; ++n){
      int col = bn + wn + n * 16 + r16;
      #pragma unroll
      for (int j = 0; j < 4; ++j){
        int row = bm + wm + m * 16 + cr + j;
        if (row >= M) continue;
        float v = acc[m][n][j];
        if (col < Nvalid){
          if (bias) v += bias[col];
          if (bng)  v = v * (bng[col] * BN_SCALE) + bnb[col];
          if (relu) v = fmaxf(v, 0.f);
        } else v = 0.f;
        C[(size_t)row * ldc + col] = f2b(v);
      }
    }
  }
}

// ---------------- residual + LayerNorm; S = LN(0.3*emb + 0.7*H) + emb (bf16 emb input) ------
__global__ __launch_bounds__(256) void k_res_ln(const uint* __restrict__ E, const uint* __restrict__ Hb,
        const float* __restrict__ g, const float* __restrict__ bb, uint* __restrict__ S){
  int row = blockIdx.x * 4 + (threadIdx.x >> 6);
  int lane = threadIdx.x & 63;
  if (row >= NW) return;
  const uint* e = E + (size_t)row * PD_U;
  const uint* h = Hb + (size_t)row * PD_U;
  float x[6], ev[6];
  float sum = 0.f, sq = 0.f;
  #pragma unroll
  for (int j = 0; j < 3; ++j){
    int i = lane + j * 64;
    float e0 = 0.f, e1 = 0.f, h0 = 0.f, h1 = 0.f;
    if (i < 150){
      uint u = h[i];
      uint ue = e[i];
      h0 = b2f_lo(u);  h1 = b2f_hi(u);
      e0 = b2f_lo(ue); e1 = b2f_hi(ue);
    }
    float v0 = 0.3f * e0 + 0.7f * h0;
    float v1 = 0.3f * e1 + 0.7f * h1;
    if (i >= 150){ v0 = 0.f; v1 = 0.f; }
    x[2*j] = v0; x[2*j+1] = v1; ev[2*j] = e0; ev[2*j+1] = e1;
    sum += v0 + v1; sq += v0 * v0 + v1 * v1;
  }
  #pragma unroll
  for (int o = 32; o > 0; o >>= 1){ sum += __shfl_down(sum, o); sq += __shfl_down(sq, o); }
  sum = __shfl(sum, 0); sq = __shfl(sq, 0);
  const float inv = 1.f / (float)DIM;
  float mu = sum * inv;
  float var = sq * inv - mu * mu;
  float rs = rsqrtf(var + 1e-5f);
  uint* o = S + (size_t)row * PD_U;
  #pragma unroll
  for (int j = 0; j < 3; ++j){
    int i = lane + j * 64;
    if (i >= PD_U) continue;
    uint w = 0;
    if (i < 150){
      float r0 = (x[2*j]   - mu) * rs * g[2*i]   + bb[2*i]   + ev[2*j];
      float r1 = (x[2*j+1] - mu) * rs * g[2*i+1] + bb[2*i+1] + ev[2*j+1];
      w = packb(r0, r1);
    }
    o[i] = w;
  }
}

// ---------------- classifier: wave per row; 64 lanes cover 75 uints (11 lanes take 2) -------
__global__ __launch_bounds__(256) void k_clf(const uint* __restrict__ h2, const float* __restrict__ w,
                      const float* __restrict__ bias, float* __restrict__ out){
  int row = blockIdx.x * 4 + (threadIdx.x >> 6);
  int lane = threadIdx.x & 63;
  if (row >= ND) return;
  float s0, s1;
  {
    uint u = h2[(size_t)row * 80 + lane];       // uints 0..63 (cols 0..127)
    float h0 = b2f_lo(u), h1 = b2f_hi(u);
    int k = 2 * lane;
    s0 = h0 * w[k] + h1 * w[k + 1];
    s1 = h0 * w[DIM2 + k] + h1 * w[DIM2 + k + 1];
  }
  if (lane < 11){
    uint u = h2[(size_t)row * 80 + 64 + lane];  // uints 64..74 (cols 128..149)
    float h0 = b2f_lo(u), h1 = b2f_hi(u);
    int k = 2 * (64 + lane);
    s0 += h0 * w[k] + h1 * w[k + 1];
    s1 += h0 * w[DIM2 + k] + h1 * w[DIM2 + k + 1];
  }
  #pragma unroll
  for (int o = 32; o > 0; o >>= 1){
    s0 += __shfl_down(s0, o);
    s1 += __shfl_down(s1, o);
  }
  if (lane == 0){
    out[row * 2]     = s0 + bias[0];
    out[row * 2 + 1] = s1 + bias[1];
  }
}

extern "C" void kernel_launch(void* const* d_in, const int* in_sizes, int n_in,
                              void* d_out, int out_size, void* d_ws, size_t ws_size,
                              hipStream_t stream){
  const int*   a_rows = (const int*)  d_in[0];
  const int*   a_cols = (const int*)  d_in[1];
  const float* a_vals = (const float*)d_in[2];
  const int*   x_rows = (const int*)  d_in[3];
  const int*   x_cols = (const int*)  d_in[4];
  const float* x_vals = (const float*)d_in[5];
  const float* emb    = (const float*)d_in[6];
  const float* w1     = (const float*)d_in[7];
  const float* w2     = (const float*)d_in[8];
  const float* w3     = (const float*)d_in[9];
  const float* ln_g   = (const float*)d_in[10];
  const float* ln_b   = (const float*)d_in[11];
  const float* m_w1   = (const float*)d_in[12];
  const float* m_b1   = (const float*)d_in[13];
  const float* bn1_g  = (const float*)d_in[14];
  const float* bn1_b  = (const float*)d_in[15];
  const float* m_w2   = (const float*)d_in[16];
  const float* m_b2   = (const float*)d_in[17];
  const float* bn2_g  = (const float*)d_in[18];
  const float* bn2_b  = (const float*)d_in[19];
  const float* clf_w  = (const float*)d_in[20];
  const float* clf_b  = (const float*)d_in[21];
  float* out = (float*)d_out;

  char* ws = (char*)d_ws;
  size_t off = 0;
  auto take = [&](size_t nbytes)->void*{
    void* p = ws + off;
    off += (nbytes + 255) & ~(size_t)255;
    return p;
  };
  int*    a_rp   = (int*)   take((NW + 1) * 4);
  int*    a_iv   = (int*)   take((size_t)NNZA * 8);
  int*    x_rp   = (int*)   take((ND + 1) * 4);
  int*    x_iv   = (int*)   take((size_t)NNZX * 8);
  int*    cursors= (int*)   take((size_t)(NW + ND) * 4);
  int*    bsA    = (int*)   take(64 * 4);
  int*    bsX    = (int*)   take(64 * 4);
  ushort* embb   = (ushort*)take((size_t)NW * PD * 2);
  ushort* Tb     = (ushort*)take((size_t)NW * PD * 2);
  ushort* Hb     = (ushort*)take((size_t)NW * PD * 2);
  ushort* w1b    = (ushort*)take((size_t)PD * PD * 2);
  ushort* w2b    = (ushort*)take((size_t)PD * PD * 2);
  ushort* w3b    = (ushort*)take((size_t)PD * PD * 2);
  ushort* mw1b   = (ushort*)take((size_t)PD * PD * 2);
  ushort* mw2b   = (ushort*)take((size_t)PD * PD * 2);
  int* curA = cursors;
  int* curX = cursors + NW;
  // doc-stage buffers alias Hb (word H3 is dead once res_ln has produced S in Tb)
  ushort* docHb = Hb;
  ushort* h1b   = Hb + (size_t)ND * PD;
  ushort* h2b   = Hb + (size_t)2 * ND * PD;  // stride 160

  // ---- fused CSR build (A and X) ----
  hipMemsetAsync(cursors, 0, (size_t)(NW + ND) * 4, stream);
  dim3 gh(cdiv(NNZA, 256), 2);
  k_hist2<<<gh, 256, 0, stream>>>(a_rows, x_rows, curA, curX);
  dim3 gb(NBA, 2);
  k_bsum2<<<gb, 1024, 0, stream>>>(curA, curX, bsA, bsX);
  k_scan_small2<<<1, 128, 0, stream>>>(bsA, bsX, a_rp, x_rp);
  k_scan_apply2<<<gb, 1024, 0, stream>>>(curA, curX, bsA, bsX, a_rp, x_rp, curA, curX);
  // ---- fused prep: interleaved scatters + all bf16 converts ----
  dim3 gp(cdiv(NW * 40, 256), 8);
  k_prep<<<gp, 256, 0, stream>>>(a_rows, a_cols, a_vals, x_rows, x_cols, x_vals,
                                 curA, curX, a_iv, x_iv,
                                 emb, embb, w1, w2, w3, m_w1, m_w2,
                                 w1b, w2b, w3b, mw1b, mw2b);

  // ---- word GCN ----
  dim3 gg(2, cdiv(NW, 128));
  k_spmm_b<<<cdiv(NW, 4), 256, 0, stream>>>(a_rp, a_iv, (const uint*)embb, (uint*)Tb, NW);
  k_mgemm<<<gg, 256, 0, stream>>>(Tb, w1b, nullptr, nullptr, nullptr, Hb, NW, DIM, PD, 1);
  k_spmm_b<<<cdiv(NW, 4), 256, 0, stream>>>(a_rp, a_iv, (const uint*)Hb, (uint*)Tb, NW);
  k_mgemm<<<gg, 256, 0, stream>>>(Tb, w2b, nullptr, nullptr, nullptr, Hb, NW, DIM, PD, 1);
  k_spmm_b<<<cdiv(NW, 4), 256, 0, stream>>>(a_rp, a_iv, (const uint*)Hb, (uint*)Tb, NW);
  k_mgemm<<<gg, 256, 0, stream>>>(Tb, w3b, nullptr, nullptr, nullptr, Hb, NW, DIM, PD, 1);
  // ---- residual + LN (S = LN + emb fused into Tb; emb read as bf16) ----
  k_res_ln<<<cdiv(NW, 4), 256, 0, stream>>>((const uint*)embb, (const uint*)Hb, ln_g, ln_b, (uint*)Tb);
  // ---- doc aggregation (single SpMM over summed matrix) ----
  k_spmm_b<<<cdiv(ND, 4), 256, 0, stream>>>(x_rp, x_iv, (const uint*)Tb, (uint*)docHb, ND);
  // ---- MLP head ----
  dim3 g1(2, cdiv(ND, 128));
  k_mgemm<<<g1, 256, 0, stream>>>(docHb, mw1b, m_b1, bn1_g, bn1_b, h1b, ND, DIM, PD, 1);
  dim3 g2(1, cdiv(ND, 128));
  k_mgemm<<<g2, 256, 0, stream>>>(h1b, mw2b, m_b2, bn2_g, bn2_b, h2b, ND, DIM2, 160, 1);
  k_clf<<<cdiv(ND, 4), 256, 0, stream>>>((const uint*)h2b, clf_w, clf_b, out);
}